// Round 1
// baseline (333.801 us; speedup 1.0000x reference)
//
#include <hip/hip_runtime.h>

// Problem constants
constexpr int B_ = 32, C_ = 256, L_ = 1024, NE = 1024;
constexpr int NPTS = B_ * L_;            // 32768 points
// d_out flat float32 layout (reference return order)
constexpr long long LOSS_OFF = 0;
constexpr long long ZQ_OFF   = 1;                         // 8,388,608 elems
constexpr long long PERP_OFF = 1 + 8388608;               // 8388609
constexpr long long OH_OFF   = PERP_OFF + 1;              // 8388610
constexpr long long IDX_OFF  = OH_OFF + 33554432LL;       // 41943042
// workspace byte offsets
constexpr size_t WS_IDX = 0;            // int[32768]
constexpr size_t WS_CNT = 131072;       // uint[1024]
constexpr size_t WS_LP  = 135168;       // float[512]
constexpr size_t WS_E2  = 137216;       // float[1024]

// ---- e2[j] = sum_k emb[j][k]^2, fp64 accumulate -> fp32 ----
__global__ __launch_bounds__(64) void k_e2(const float* __restrict__ emb,
                                           float* __restrict__ e2) {
  const int j = blockIdx.x;
  const int t = threadIdx.x;
  const float* row = emb + (size_t)j * C_;
  double s = 0.0;
#pragma unroll
  for (int q = 0; q < 4; ++q) {
    float v = row[t + 64 * q];
    s += (double)v * (double)v;
  }
#pragma unroll
  for (int off = 32; off > 0; off >>= 1) s += __shfl_down(s, off);
  if (t == 0) e2[j] = (float)s;
}

// ---- distance + argmin: 64 points x 1024 codes per block ----
// K-major LDS tiles; 4x4 micro-tile per thread (16x16 thread grid).
__global__ __launch_bounds__(256) void k_dist(const float* __restrict__ z,
                                              const float* __restrict__ emb,
                                              const float* __restrict__ e2g,
                                              int* __restrict__ idxw,
                                              unsigned int* __restrict__ counts,
                                              float* __restrict__ idx_out) {
  __shared__ float zs[256][68];   // [k][l']  (68 pad: b128-aligned rows, 2-way max conflict)
  __shared__ float es[256][68];   // [k][c']
  __shared__ float z2s[64];
  __shared__ float red_d[64][17];
  __shared__ int   red_i[64][17];

  const int tid = threadIdx.x;
  const int bid = blockIdx.x;
  const int b  = bid >> 4;
  const int l0 = (bid & 15) << 6;
  const int n0 = bid << 6;

  // stage z tile: zs[k][l'] = z[b][k][l0+l']   (coalesced float4 along l)
  {
    const float4* z4 = reinterpret_cast<const float4*>(z + (size_t)b * C_ * L_ + l0);
    const int l4 = tid & 15;
    const int kk = tid >> 4;
#pragma unroll
    for (int rep = 0; rep < 16; ++rep) {
      int k = rep * 16 + kk;
      float4 v = z4[(size_t)k * (L_ / 4) + l4];
      *reinterpret_cast<float4*>(&zs[k][l4 * 4]) = v;
    }
  }
  __syncthreads();

  // z2 per point, fp64 accumulate (numpy-faithful within 1 ulp)
  if (tid < 64) {
    double s = 0.0;
#pragma unroll 8
    for (int k = 0; k < 256; ++k) {
      float v = zs[k][tid];
      s += (double)v * (double)v;
    }
    z2s[tid] = (float)s;
  }
  __syncthreads();

  const int tx = tid & 15;   // code group
  const int ty = tid >> 4;   // point group
  float z2r[4];
#pragma unroll
  for (int i = 0; i < 4; ++i) z2r[i] = z2s[ty * 4 + i];

  float bestd[4];
  int   besti[4];
#pragma unroll
  for (int i = 0; i < 4; ++i) { bestd[i] = 3.4e38f; besti[i] = 0; }

  for (int chunk = 0; chunk < 16; ++chunk) {
    const int c0 = chunk << 6;
    // stage es[k][c] = emb[c0+c][k]  (64B-coalesced global reads, transposed LDS write)
    {
      const int c  = tid >> 2;
      const int kq = tid & 3;
      const float4* e4 = reinterpret_cast<const float4*>(emb + (size_t)(c0 + c) * C_);
#pragma unroll
      for (int rep = 0; rep < 16; ++rep) {
        int k4 = rep * 4 + kq;
        float4 v = e4[k4];
        es[k4 * 4 + 0][c] = v.x;
        es[k4 * 4 + 1][c] = v.y;
        es[k4 * 4 + 2][c] = v.z;
        es[k4 * 4 + 3][c] = v.w;
      }
    }
    __syncthreads();

    float acc[4][4];
#pragma unroll
    for (int i = 0; i < 4; ++i)
#pragma unroll
      for (int j = 0; j < 4; ++j) acc[i][j] = 0.f;

#pragma unroll 8
    for (int k = 0; k < 256; ++k) {
      float zr[4], er[4];
      *reinterpret_cast<float4*>(zr) = *reinterpret_cast<const float4*>(&zs[k][ty * 4]);
      *reinterpret_cast<float4*>(er) = *reinterpret_cast<const float4*>(&es[k][tx * 4]);
#pragma unroll
      for (int i = 0; i < 4; ++i)
#pragma unroll
        for (int j = 0; j < 4; ++j) acc[i][j] = fmaf(zr[i], er[j], acc[i][j]);
    }

    float e2r[4];
#pragma unroll
    for (int j = 0; j < 4; ++j) e2r[j] = e2g[c0 + tx * 4 + j];
#pragma unroll
    for (int i = 0; i < 4; ++i) {
#pragma unroll
      for (int j = 0; j < 4; ++j) {
        // numpy op order: fl(fl(z2+e2) - 2*dot); 2*acc exact so contraction-safe
        float d = (z2r[i] + e2r[j]) - 2.0f * acc[i][j];
        int ci = c0 + tx * 4 + j;
        if (d < bestd[i]) { bestd[i] = d; besti[i] = ci; }  // strict <: first-index ties
      }
    }
    __syncthreads();
  }

#pragma unroll
  for (int i = 0; i < 4; ++i) {
    red_d[ty * 4 + i][tx] = bestd[i];
    red_i[ty * 4 + i][tx] = besti[i];
  }
  __syncthreads();
  if (tid < 64) {
    float bd = red_d[tid][0];
    int   bi = red_i[tid][0];
#pragma unroll
    for (int t = 1; t < 16; ++t) {
      float d = red_d[tid][t];
      int  ii = red_i[tid][t];
      if (d < bd || (d == bd && ii < bi)) { bd = d; bi = ii; }
    }
    const int n = n0 + tid;
    idxw[n] = bi;
    idx_out[n] = (float)bi;
    atomicAdd(&counts[bi], 1u);
  }
}

// ---- fused gather (z_q straight-through) + masked loss partials ----
__global__ __launch_bounds__(256) void k_zq_loss(const float* __restrict__ z,
                                                 const float* __restrict__ emb,
                                                 const float* __restrict__ mask,
                                                 const int* __restrict__ idxw,
                                                 float* __restrict__ zq_out,
                                                 float* __restrict__ lp) {
  __shared__ float eq[256][66];  // [c][l']  codebook rows for this tile's 64 ids
  __shared__ float red[256];
  const int tid = threadIdx.x, bid = blockIdx.x;
  const int b = bid >> 4, l0 = (bid & 15) << 6, n0 = bid << 6;
  {
    const int r  = tid >> 2;
    const int kq = tid & 3;
    const int id = idxw[n0 + r];
    const float4* e4 = reinterpret_cast<const float4*>(emb + (size_t)id * C_);
#pragma unroll
    for (int rep = 0; rep < 16; ++rep) {
      int c4 = rep * 4 + kq;
      float4 v = e4[c4];
      eq[c4 * 4 + 0][r] = v.x;
      eq[c4 * 4 + 1][r] = v.y;
      eq[c4 * 4 + 2][r] = v.z;
      eq[c4 * 4 + 3][r] = v.w;
    }
  }
  __syncthreads();
  const int lq = tid & 63, cg = tid >> 6;
  const float m = mask[b * L_ + l0 + lq];
  const size_t zbase = (size_t)b * C_ * L_ + l0 + lq;
  float s = 0.f;
#pragma unroll 4
  for (int ci = 0; ci < 64; ++ci) {
    int c = cg * 64 + ci;
    float zv = z[zbase + (size_t)c * L_];
    float q  = eq[c][lq];
    float diff = q - zv;                     // fl(z_q - zp)
    zq_out[zbase + (size_t)c * L_] = zv + diff;  // straight-through: fl(zp + fl(z_q-zp))
    float t = diff * m;
    s = fmaf(t, t, s);
  }
  red[tid] = s;
  __syncthreads();
  for (int off = 128; off > 0; off >>= 1) {
    if (tid < off) red[tid] += red[tid + off];
    __syncthreads();
  }
  if (tid == 0) lp[bid] = red[0];
}

// ---- one_hot: single pass, compute values on the fly (base only 8B-aligned) ----
__global__ __launch_bounds__(256) void k_onehot(const int* __restrict__ idxw,
                                                float* __restrict__ oh) {
  const int tid = threadIdx.x, bid = blockIdx.x;
#pragma unroll
  for (int r = 0; r < 16; ++r) {
    const int n = bid * 16 + r;
    const int id = idxw[n];
    float* row = oh + (size_t)n * NE;
    const int c = tid * 4;
    float2 v0, v1;
    v0.x = (c + 0 == id) ? 1.f : 0.f;
    v0.y = (c + 1 == id) ? 1.f : 0.f;
    v1.x = (c + 2 == id) ? 1.f : 0.f;
    v1.y = (c + 3 == id) ? 1.f : 0.f;
    *reinterpret_cast<float2*>(row + c)     = v0;
    *reinterpret_cast<float2*>(row + c + 2) = v1;
  }
}

// ---- deterministic loss total + perplexity ----
__global__ __launch_bounds__(256) void k_final(const float* __restrict__ lp,
                                               const unsigned int* __restrict__ counts,
                                               float* __restrict__ out) {
  __shared__ float red[256];
  const int t = threadIdx.x;
  red[t] = lp[t] + lp[t + 256];
  __syncthreads();
  for (int off = 128; off > 0; off >>= 1) {
    if (t < off) red[t] += red[t + off];
    __syncthreads();
  }
  if (t == 0) {
    float m = red[0] / 8388608.0f;
    out[LOSS_OFF] = m + 0.25f * m;  // commitment + BETA*codebook (equal forward values)
  }
  __syncthreads();
  float h = 0.f;
#pragma unroll
  for (int q = 0; q < 4; ++q) {
    int jj = t * 4 + q;
    float em = (float)counts[jj] * (1.0f / 32768.0f);
    h += em * logf(em + 1e-10f);
  }
  red[t] = h;
  __syncthreads();
  for (int off = 128; off > 0; off >>= 1) {
    if (t < off) red[t] += red[t + off];
    __syncthreads();
  }
  if (t == 0) out[PERP_OFF] = expf(-red[0]);
}

extern "C" void kernel_launch(void* const* d_in, const int* in_sizes, int n_in,
                              void* d_out, int out_size, void* d_ws, size_t ws_size,
                              hipStream_t stream) {
  const float* z    = (const float*)d_in[0];
  const float* mask = (const float*)d_in[1];
  const float* emb  = (const float*)d_in[2];
  float* out = (float*)d_out;
  char* ws = (char*)d_ws;
  int* idxw            = (int*)(ws + WS_IDX);
  unsigned int* counts = (unsigned int*)(ws + WS_CNT);
  float* lp            = (float*)(ws + WS_LP);
  float* e2            = (float*)(ws + WS_E2);

  hipMemsetAsync(counts, 0, NE * sizeof(unsigned int), stream);
  hipLaunchKernelGGL(k_e2, dim3(NE), dim3(64), 0, stream, emb, e2);
  hipLaunchKernelGGL(k_dist, dim3(512), dim3(256), 0, stream,
                     z, emb, e2, idxw, counts, out + IDX_OFF);
  hipLaunchKernelGGL(k_zq_loss, dim3(512), dim3(256), 0, stream,
                     z, emb, mask, idxw, out + ZQ_OFF, lp);
  hipLaunchKernelGGL(k_onehot, dim3(NPTS / 16), dim3(256), 0, stream,
                     idxw, out + OH_OFF);
  hipLaunchKernelGGL(k_final, dim3(1), dim3(256), 0, stream, lp, counts, out);
}

// Round 2
// 303.763 us; speedup vs baseline: 1.0989x; 1.0989x over previous
//
#include <hip/hip_runtime.h>

// Problem constants
constexpr int B_ = 32, C_ = 256, L_ = 1024, NE = 1024;
constexpr int NPTS = B_ * L_;            // 32768 points
// d_out flat float32 layout (reference return order)
constexpr long long LOSS_OFF = 0;
constexpr long long ZQ_OFF   = 1;                         // 8,388,608 elems
constexpr long long PERP_OFF = 1 + 8388608;               // 8388609
constexpr long long OH_OFF   = PERP_OFF + 1;              // 8388610
constexpr long long IDX_OFF  = OH_OFF + 33554432LL;       // 41943042
// workspace byte offsets
constexpr size_t WS_IDX = 0;            // int[32768]
constexpr size_t WS_CNT = 131072;       // uint[1024]
constexpr size_t WS_LP  = 135168;       // float[512]
constexpr size_t WS_E2  = 137216;       // float[1024]
constexpr size_t WS_Z2  = 141312;       // float[32768]

// ---- e2[j] = sum_k emb[j][k]^2, fp64 accumulate -> fp32 ----
__global__ __launch_bounds__(64) void k_e2(const float* __restrict__ emb,
                                           float* __restrict__ e2) {
  const int j = blockIdx.x;
  const int t = threadIdx.x;
  const float* row = emb + (size_t)j * C_;
  double s = 0.0;
#pragma unroll
  for (int q = 0; q < 4; ++q) {
    float v = row[t + 64 * q];
    s += (double)v * (double)v;
  }
#pragma unroll
  for (int off = 32; off > 0; off >>= 1) s += __shfl_down(s, off);
  if (t == 0) e2[j] = (float)s;
}

// ---- z2[n] = sum_k z[b][k][l]^2, fp64, coalesced along l ----
__global__ __launch_bounds__(256) void k_z2(const float* __restrict__ z,
                                            float* __restrict__ z2) {
  __shared__ double rd[256];
  const int tid = threadIdx.x, bid = blockIdx.x;
  const int b = bid >> 4, l0 = (bid & 15) << 6;
  const int li = tid & 63, kk = tid >> 6;
  const int l = l0 + li;
  const float* zp = z + (size_t)b * C_ * L_ + l;
  double s = 0.0;
#pragma unroll 8
  for (int k = kk * 64; k < kk * 64 + 64; ++k) {
    float v = zp[(size_t)k * L_];
    s += (double)v * (double)v;
  }
  rd[tid] = s;
  __syncthreads();
  if (kk == 0) {
    double t0 = rd[li] + rd[64 + li] + rd[128 + li] + rd[192 + li];
    z2[b * L_ + l] = (float)t0;
  }
}

// ---- distance + partial argmin: 64 points x 512 codes per block ----
// K chunked at 64 so LDS = 50 KB -> 3 blocks/CU (12 waves/CU).
// acc order over k = 0..255 sequential fp32 FMA: bit-identical to the
// previously-passing full-K variant -> argmin matches numpy.
__global__ __launch_bounds__(256, 3) void k_dist(const float* __restrict__ z,
                                                 const float* __restrict__ emb,
                                                 const float* __restrict__ e2g,
                                                 const float* __restrict__ z2g,
                                                 float* __restrict__ bd_ws,
                                                 int* __restrict__ bi_ws) {
  __shared__ float zs[64][68];          // [k'][l']  17,408 B
  __shared__ float es_mem[64 * 128];    // [k'][c']  32,768 B (aliased for reduce)
  float (*red_d)[17] = reinterpret_cast<float(*)[17]>(es_mem);
  int   (*red_i)[17] = reinterpret_cast<int(*)[17]>(es_mem + 64 * 17);

  const int tid = threadIdx.x;
  const int bid = blockIdx.x;
  const int h = bid & 1;                // code half
  const int t = bid >> 1;
  const int b  = t >> 4;
  const int l0 = (t & 15) << 6;
  const int n0 = t << 6;
  const int cbase = h << 9;             // 0 or 512

  const int tx = tid & 15;              // code group
  const int ty = tid >> 4;              // point group

  float z2r[4];
#pragma unroll
  for (int i = 0; i < 4; ++i) z2r[i] = z2g[n0 + ty * 4 + i];

  float bestd[4];
  int   besti[4];
#pragma unroll
  for (int i = 0; i < 4; ++i) { bestd[i] = 3.4e38f; besti[i] = 0; }

  for (int cc = 0; cc < 4; ++cc) {
    float acc[4][8];
#pragma unroll
    for (int i = 0; i < 4; ++i)
#pragma unroll
      for (int j = 0; j < 8; ++j) acc[i][j] = 0.f;

    for (int kc = 0; kc < 4; ++kc) {
      const int k0 = kc << 6;
      __syncthreads();
      // stage zs[k][l'] = z[b][k0+k][l0+l'] (float4 coalesced along l)
      {
        const int l4 = tid & 15;
        const int kr = tid >> 4;
        const float4* z4 = reinterpret_cast<const float4*>(z + (size_t)b * C_ * L_ + l0);
#pragma unroll
        for (int rep = 0; rep < 4; ++rep) {
          int k = rep * 16 + kr;
          float4 v = z4[(size_t)(k0 + k) * (L_ / 4) + l4];
          *reinterpret_cast<float4*>(&zs[k][l4 * 4]) = v;
        }
      }
      // stage es[k][c] = emb[cbase+cc*128+c][k0+k] (transposed write)
      {
        const int c  = tid >> 1;
        const int kq = tid & 1;
        const float4* e4 = reinterpret_cast<const float4*>(
            emb + (size_t)(cbase + (cc << 7) + c) * C_) + (k0 >> 2);
#pragma unroll
        for (int r = 0; r < 8; ++r) {
          int k4 = kq * 8 + r;
          float4 v = e4[k4];
          es_mem[(k4 * 4 + 0) * 128 + c] = v.x;
          es_mem[(k4 * 4 + 1) * 128 + c] = v.y;
          es_mem[(k4 * 4 + 2) * 128 + c] = v.z;
          es_mem[(k4 * 4 + 3) * 128 + c] = v.w;
        }
      }
      __syncthreads();

#pragma unroll 8
      for (int k = 0; k < 64; ++k) {
        float zr[4], er[8];
        *reinterpret_cast<float4*>(zr) = *reinterpret_cast<const float4*>(&zs[k][ty * 4]);
        *reinterpret_cast<float4*>(&er[0]) =
            *reinterpret_cast<const float4*>(&es_mem[k * 128 + tx * 4]);
        *reinterpret_cast<float4*>(&er[4]) =
            *reinterpret_cast<const float4*>(&es_mem[k * 128 + 64 + tx * 4]);
#pragma unroll
        for (int i = 0; i < 4; ++i)
#pragma unroll
          for (int j = 0; j < 8; ++j) acc[i][j] = fmaf(zr[i], er[j], acc[i][j]);
      }
    }

    // fold this 128-code chunk into the running best (codes ascending per thread)
    float e2r[8];
#pragma unroll
    for (int j = 0; j < 8; ++j) {
      int code = cbase + (cc << 7) + ((j < 4) ? (tx * 4 + j) : (64 + tx * 4 + (j - 4)));
      e2r[j] = e2g[code];
    }
#pragma unroll
    for (int j = 0; j < 8; ++j) {
      int code = cbase + (cc << 7) + ((j < 4) ? (tx * 4 + j) : (64 + tx * 4 + (j - 4)));
#pragma unroll
      for (int i = 0; i < 4; ++i) {
        float d = (z2r[i] + e2r[j]) - 2.0f * acc[i][j];  // numpy op order
        if (d < bestd[i]) { bestd[i] = d; besti[i] = code; }
      }
    }
  }

  __syncthreads();  // es reads done; safe to alias reduce arrays
#pragma unroll
  for (int i = 0; i < 4; ++i) {
    red_d[ty * 4 + i][tx] = bestd[i];
    red_i[ty * 4 + i][tx] = besti[i];
  }
  __syncthreads();
  if (tid < 64) {
    float bd = red_d[tid][0];
    int   bi = red_i[tid][0];
#pragma unroll
    for (int q = 1; q < 16; ++q) {
      float d = red_d[tid][q];
      int  ii = red_i[tid][q];
      if (d < bd || (d == bd && ii < bi)) { bd = d; bi = ii; }
    }
    const int n = n0 + tid;
    bd_ws[(h << 15) + n] = bd;
    bi_ws[(h << 15) + n] = bi;
  }
}

// ---- merge the two code-half partials; histogram ----
__global__ __launch_bounds__(256) void k_merge(const float* __restrict__ bd_ws,
                                               const int* __restrict__ bi_ws,
                                               int* __restrict__ idxw,
                                               unsigned int* __restrict__ counts,
                                               float* __restrict__ idx_out) {
  const int n = blockIdx.x * 256 + threadIdx.x;
  float d0 = bd_ws[n], d1 = bd_ws[NPTS + n];
  int   i0 = bi_ws[n], i1 = bi_ws[NPTS + n];
  // half-0 codes are all smaller indices: tie -> half 0 (strict <)
  int   bi = (d1 < d0) ? i1 : i0;
  idxw[n] = bi;
  idx_out[n] = (float)bi;
  atomicAdd(&counts[bi], 1u);
}

// ---- fused gather (z_q straight-through) + masked loss partials ----
__global__ __launch_bounds__(256) void k_zq_loss(const float* __restrict__ z,
                                                 const float* __restrict__ emb,
                                                 const float* __restrict__ mask,
                                                 const int* __restrict__ idxw,
                                                 float* __restrict__ zq_out,
                                                 float* __restrict__ lp) {
  __shared__ float eq[256][66];  // [c][l']  codebook rows for this tile's 64 ids
  __shared__ float red[256];
  const int tid = threadIdx.x, bid = blockIdx.x;
  const int b = bid >> 4, l0 = (bid & 15) << 6, n0 = bid << 6;
  {
    const int r  = tid >> 2;
    const int kq = tid & 3;
    const int id = idxw[n0 + r];
    const float4* e4 = reinterpret_cast<const float4*>(emb + (size_t)id * C_);
#pragma unroll
    for (int rep = 0; rep < 16; ++rep) {
      int c4 = rep * 4 + kq;
      float4 v = e4[c4];
      eq[c4 * 4 + 0][r] = v.x;
      eq[c4 * 4 + 1][r] = v.y;
      eq[c4 * 4 + 2][r] = v.z;
      eq[c4 * 4 + 3][r] = v.w;
    }
  }
  __syncthreads();
  const int lq = tid & 63, cg = tid >> 6;
  const float m = mask[b * L_ + l0 + lq];
  const size_t zbase = (size_t)b * C_ * L_ + l0 + lq;
  float s = 0.f;
#pragma unroll 4
  for (int ci = 0; ci < 64; ++ci) {
    int c = cg * 64 + ci;
    float zv = z[zbase + (size_t)c * L_];
    float q  = eq[c][lq];
    float diff = q - zv;                         // fl(z_q - zp)
    zq_out[zbase + (size_t)c * L_] = zv + diff;  // straight-through
    float t = diff * m;
    s = fmaf(t, t, s);
  }
  red[tid] = s;
  __syncthreads();
  for (int off = 128; off > 0; off >>= 1) {
    if (tid < off) red[tid] += red[tid + off];
    __syncthreads();
  }
  if (tid == 0) lp[bid] = red[0];
}

// ---- one_hot: single pass, values on the fly (base only 8B-aligned) ----
__global__ __launch_bounds__(256) void k_onehot(const int* __restrict__ idxw,
                                                float* __restrict__ oh) {
  const int tid = threadIdx.x, bid = blockIdx.x;
#pragma unroll
  for (int r = 0; r < 16; ++r) {
    const int n = bid * 16 + r;
    const int id = idxw[n];
    float* row = oh + (size_t)n * NE;
    const int c = tid * 4;
    float2 v0, v1;
    v0.x = (c + 0 == id) ? 1.f : 0.f;
    v0.y = (c + 1 == id) ? 1.f : 0.f;
    v1.x = (c + 2 == id) ? 1.f : 0.f;
    v1.y = (c + 3 == id) ? 1.f : 0.f;
    *reinterpret_cast<float2*>(row + c)     = v0;
    *reinterpret_cast<float2*>(row + c + 2) = v1;
  }
}

// ---- deterministic loss total + perplexity ----
__global__ __launch_bounds__(256) void k_final(const float* __restrict__ lp,
                                               const unsigned int* __restrict__ counts,
                                               float* __restrict__ out) {
  __shared__ float red[256];
  const int t = threadIdx.x;
  red[t] = lp[t] + lp[t + 256];
  __syncthreads();
  for (int off = 128; off > 0; off >>= 1) {
    if (t < off) red[t] += red[t + off];
    __syncthreads();
  }
  if (t == 0) {
    float m = red[0] / 8388608.0f;
    out[LOSS_OFF] = m + 0.25f * m;
  }
  __syncthreads();
  float h = 0.f;
#pragma unroll
  for (int q = 0; q < 4; ++q) {
    int jj = t * 4 + q;
    float em = (float)counts[jj] * (1.0f / 32768.0f);
    h += em * logf(em + 1e-10f);
  }
  red[t] = h;
  __syncthreads();
  for (int off = 128; off > 0; off >>= 1) {
    if (t < off) red[t] += red[t + off];
    __syncthreads();
  }
  if (t == 0) out[PERP_OFF] = expf(-red[0]);
}

extern "C" void kernel_launch(void* const* d_in, const int* in_sizes, int n_in,
                              void* d_out, int out_size, void* d_ws, size_t ws_size,
                              hipStream_t stream) {
  const float* z    = (const float*)d_in[0];
  const float* mask = (const float*)d_in[1];
  const float* emb  = (const float*)d_in[2];
  float* out = (float*)d_out;
  char* ws = (char*)d_ws;
  int* idxw            = (int*)(ws + WS_IDX);
  unsigned int* counts = (unsigned int*)(ws + WS_CNT);
  float* lp            = (float*)(ws + WS_LP);
  float* e2            = (float*)(ws + WS_E2);
  float* z2            = (float*)(ws + WS_Z2);
  // argmin partials live in the one_hot region of d_out (overwritten later
  // by k_onehot; 512 KB << 134 MB)
  float* bd_ws = out + OH_OFF;
  int*   bi_ws = (int*)(out + OH_OFF) + NPTS * 2;

  hipMemsetAsync(counts, 0, NE * sizeof(unsigned int), stream);
  hipLaunchKernelGGL(k_e2, dim3(NE), dim3(64), 0, stream, emb, e2);
  hipLaunchKernelGGL(k_z2, dim3(512), dim3(256), 0, stream, z, z2);
  hipLaunchKernelGGL(k_dist, dim3(1024), dim3(256), 0, stream,
                     z, emb, e2, z2, bd_ws, bi_ws);
  hipLaunchKernelGGL(k_merge, dim3(NPTS / 256), dim3(256), 0, stream,
                     bd_ws, bi_ws, idxw, counts, out + IDX_OFF);
  hipLaunchKernelGGL(k_zq_loss, dim3(512), dim3(256), 0, stream,
                     z, emb, mask, idxw, out + ZQ_OFF, lp);
  hipLaunchKernelGGL(k_onehot, dim3(NPTS / 16), dim3(256), 0, stream,
                     idxw, out + OH_OFF);
  hipLaunchKernelGGL(k_final, dim3(1), dim3(256), 0, stream, lp, counts, out);
}

// Round 3
// 265.863 us; speedup vs baseline: 1.2555x; 1.1426x over previous
//
#include <hip/hip_runtime.h>

// Problem constants
constexpr int B_ = 32, C_ = 256, L_ = 1024, NE = 1024;
constexpr int NPTS = B_ * L_;            // 32768 points
// d_out flat float32 layout (reference return order)
constexpr long long LOSS_OFF = 0;
constexpr long long ZQ_OFF   = 1;                         // 8,388,608 elems
constexpr long long PERP_OFF = 1 + 8388608;               // 8388609
constexpr long long OH_OFF   = PERP_OFF + 1;              // 8388610
constexpr long long IDX_OFF  = OH_OFF + 33554432LL;       // 41943042
// workspace byte offsets
constexpr size_t WS_IDX = 0;            // int[32768]
constexpr size_t WS_CNT = 131072;       // uint[1024]
constexpr size_t WS_LP  = 135168;       // float[512]
constexpr size_t WS_E2  = 137216;       // float[1024]
constexpr size_t WS_Z2  = 141312;       // float[32768]

// ---- e2[j] = sum_k emb[j][k]^2, fp64 accumulate -> fp32 ----
__global__ __launch_bounds__(64) void k_e2(const float* __restrict__ emb,
                                           float* __restrict__ e2) {
  const int j = blockIdx.x;
  const int t = threadIdx.x;
  const float* row = emb + (size_t)j * C_;
  double s = 0.0;
#pragma unroll
  for (int q = 0; q < 4; ++q) {
    float v = row[t + 64 * q];
    s += (double)v * (double)v;
  }
#pragma unroll
  for (int off = 32; off > 0; off >>= 1) s += __shfl_down(s, off);
  if (t == 0) e2[j] = (float)s;
}

// ---- z2[n] = sum_k z[b][k][l]^2, fp64, coalesced along l ----
__global__ __launch_bounds__(256) void k_z2(const float* __restrict__ z,
                                            float* __restrict__ z2) {
  __shared__ double rd[256];
  const int tid = threadIdx.x, bid = blockIdx.x;
  const int b = bid >> 4, l0 = (bid & 15) << 6;
  const int li = tid & 63, kk = tid >> 6;
  const int l = l0 + li;
  const float* zp = z + (size_t)b * C_ * L_ + l;
  double s = 0.0;
#pragma unroll 8
  for (int k = kk * 64; k < kk * 64 + 64; ++k) {
    float v = zp[(size_t)k * L_];
    s += (double)v * (double)v;
  }
  rd[tid] = s;
  __syncthreads();
  if (kk == 0) {
    double t0 = rd[li] + rd[64 + li] + rd[128 + li] + rd[192 + li];
    z2[b * L_ + l] = (float)t0;
  }
}

// ---- distance + partial argmin: 128 points x 256 codes per block ----
// 8x16 micro-tile: 6 ds_read_b128 per 128 FMA (0.75 B/FMA, LDS pipe ~75%).
// k accumulates 0..255 sequential fp32 FMA -> bit-identical to the passing
// R2 kernel's dot chain -> argmin matches numpy.
__global__ __launch_bounds__(256, 2) void k_dist(const float* __restrict__ z,
                                                 const float* __restrict__ emb,
                                                 const float* __restrict__ e2g,
                                                 const float* __restrict__ z2g,
                                                 float* __restrict__ bd_ws,
                                                 int* __restrict__ bi_ws) {
  __shared__ float zs[32][128];     // [k'][l']  16 KB
  __shared__ float es[32 * 256];    // [k'][code, sub-read layout] 32 KB (aliased)
  float (*red_d)[17] = reinterpret_cast<float(*)[17]>(es);
  int   (*red_i)[17] = reinterpret_cast<int(*)[17]>(es + 128 * 17);

  const int tid = threadIdx.x;
  const int bid = blockIdx.x;
  const int tile = bid >> 2;            // 256 point tiles
  const int quarter = bid & 3;          // 4 code quarters of 256
  const int b  = tile >> 3;
  const int l0 = (tile & 7) << 7;
  const int n0 = tile << 7;
  const int c0 = quarter << 8;
  const int tx = tid & 15;              // code group (16 codes each)
  const int ty = tid >> 4;              // point group (8 points each)

  float acc[8][16];
#pragma unroll
  for (int i = 0; i < 8; ++i)
#pragma unroll
    for (int j = 0; j < 16; ++j) acc[i][j] = 0.f;

  const int l4 = tid & 31, kr = tid >> 5;
  const float4* z4 = reinterpret_cast<const float4*>(z + (size_t)b * (C_ * L_) + l0);
  // es write slot for code c=tid: matches read addr r*64 + tx*4 + q
  const int wbase = ((tid >> 2) & 3) * 64 + (tid >> 4) * 4 + (tid & 3);

  for (int kc = 0; kc < 8; ++kc) {
    const int k0 = kc << 5;
    __syncthreads();
    // stage zs[k][l'] = z[b][k0+k][l0+l']  (float4, coalesced along l)
#pragma unroll
    for (int rep = 0; rep < 4; ++rep) {
      int k = rep * 8 + kr;
      float4 v = z4[(size_t)(k0 + k) * (L_ / 4) + l4];
      *reinterpret_cast<float4*>(&zs[k][l4 * 4]) = v;
    }
    // stage es: thread tid owns code c0+tid, loads its 32 K-values (L2-hot)
    {
      const float4* e4 = reinterpret_cast<const float4*>(
          emb + (size_t)(c0 + tid) * C_ + k0);
#pragma unroll
      for (int k4 = 0; k4 < 8; ++k4) {
        float4 v = e4[k4];
        es[(k4 * 4 + 0) * 256 + wbase] = v.x;
        es[(k4 * 4 + 1) * 256 + wbase] = v.y;
        es[(k4 * 4 + 2) * 256 + wbase] = v.z;
        es[(k4 * 4 + 3) * 256 + wbase] = v.w;
      }
    }
    __syncthreads();

#pragma unroll 2
    for (int k = 0; k < 32; ++k) {
      float zr[8], er[16];
      *reinterpret_cast<float4*>(&zr[0]) =
          *reinterpret_cast<const float4*>(&zs[k][ty * 8]);
      *reinterpret_cast<float4*>(&zr[4]) =
          *reinterpret_cast<const float4*>(&zs[k][ty * 8 + 4]);
#pragma unroll
      for (int r = 0; r < 4; ++r)
        *reinterpret_cast<float4*>(&er[r * 4]) =
            *reinterpret_cast<const float4*>(&es[k * 256 + r * 64 + tx * 4]);
#pragma unroll
      for (int i = 0; i < 8; ++i)
#pragma unroll
        for (int j = 0; j < 16; ++j) acc[i][j] = fmaf(zr[i], er[j], acc[i][j]);
    }
  }

  // fold distances, per-thread argmin over this thread's 16 ascending codes
  float e2r[16];
#pragma unroll
  for (int r = 0; r < 4; ++r)
    *reinterpret_cast<float4*>(&e2r[r * 4]) =
        *reinterpret_cast<const float4*>(&e2g[c0 + tx * 16 + r * 4]);
  float z2r[8];
#pragma unroll
  for (int r = 0; r < 2; ++r)
    *reinterpret_cast<float4*>(&z2r[r * 4]) =
        *reinterpret_cast<const float4*>(&z2g[n0 + ty * 8 + r * 4]);

  float bestd[8];
  int   besti[8];
#pragma unroll
  for (int i = 0; i < 8; ++i) { bestd[i] = 3.4e38f; besti[i] = 0; }
#pragma unroll
  for (int j = 0; j < 16; ++j) {
    const int code = c0 + tx * 16 + j;
#pragma unroll
    for (int i = 0; i < 8; ++i) {
      float d = (z2r[i] + e2r[j]) - 2.0f * acc[i][j];   // numpy op order
      if (d < bestd[i]) { bestd[i] = d; besti[i] = code; }  // strict <
    }
  }

  __syncthreads();  // es reads done; safe to alias reduce arrays
#pragma unroll
  for (int i = 0; i < 8; ++i) {
    red_d[ty * 8 + i][tx] = bestd[i];
    red_i[ty * 8 + i][tx] = besti[i];
  }
  __syncthreads();
  if (tid < 128) {
    float bd = red_d[tid][0];
    int   bi = red_i[tid][0];
#pragma unroll
    for (int q = 1; q < 16; ++q) {
      float d = red_d[tid][q];
      int  ii = red_i[tid][q];
      if (d < bd || (d == bd && ii < bi)) { bd = d; bi = ii; }
    }
    bd_ws[quarter * NPTS + n0 + tid] = bd;
    bi_ws[quarter * NPTS + n0 + tid] = bi;
  }
}

// ---- merge the four code-quarter partials; histogram ----
__global__ __launch_bounds__(256) void k_merge(const float* __restrict__ bd_ws,
                                               const int* __restrict__ bi_ws,
                                               int* __restrict__ idxw,
                                               unsigned int* __restrict__ counts,
                                               float* __restrict__ idx_out) {
  const int n = blockIdx.x * 256 + threadIdx.x;
  float bd = bd_ws[n];
  int   bi = bi_ws[n];
#pragma unroll
  for (int q = 1; q < 4; ++q) {
    float d = bd_ws[q * NPTS + n];
    int  ii = bi_ws[q * NPTS + n];
    if (d < bd) { bd = d; bi = ii; }   // quarters ascending: tie -> lower code
  }
  idxw[n] = bi;
  idx_out[n] = (float)bi;
  atomicAdd(&counts[bi], 1u);
}

// ---- fused gather (z_q straight-through) + masked loss partials ----
__global__ __launch_bounds__(256) void k_zq_loss(const float* __restrict__ z,
                                                 const float* __restrict__ emb,
                                                 const float* __restrict__ mask,
                                                 const int* __restrict__ idxw,
                                                 float* __restrict__ zq_out,
                                                 float* __restrict__ lp) {
  __shared__ float eq[256][66];  // [c][l']  codebook rows for this tile's 64 ids
  __shared__ float red[256];
  const int tid = threadIdx.x, bid = blockIdx.x;
  const int b = bid >> 4, l0 = (bid & 15) << 6, n0 = bid << 6;
  {
    const int r  = tid >> 2;
    const int kq = tid & 3;
    const int id = idxw[n0 + r];
    const float4* e4 = reinterpret_cast<const float4*>(emb + (size_t)id * C_);
#pragma unroll
    for (int rep = 0; rep < 16; ++rep) {
      int c4 = rep * 4 + kq;
      float4 v = e4[c4];
      eq[c4 * 4 + 0][r] = v.x;
      eq[c4 * 4 + 1][r] = v.y;
      eq[c4 * 4 + 2][r] = v.z;
      eq[c4 * 4 + 3][r] = v.w;
    }
  }
  __syncthreads();
  const int lq = tid & 63, cg = tid >> 6;
  const float m = mask[b * L_ + l0 + lq];
  const size_t zbase = (size_t)b * C_ * L_ + l0 + lq;
  float s = 0.f;
#pragma unroll 4
  for (int ci = 0; ci < 64; ++ci) {
    int c = cg * 64 + ci;
    float zv = z[zbase + (size_t)c * L_];
    float q  = eq[c][lq];
    float diff = q - zv;                         // fl(z_q - zp)
    zq_out[zbase + (size_t)c * L_] = zv + diff;  // straight-through
    float t = diff * m;
    s = fmaf(t, t, s);
  }
  red[tid] = s;
  __syncthreads();
  for (int off = 128; off > 0; off >>= 1) {
    if (tid < off) red[tid] += red[tid + off];
    __syncthreads();
  }
  if (tid == 0) lp[bid] = red[0];
}

// ---- one_hot: single pass, values on the fly (base only 8B-aligned) ----
__global__ __launch_bounds__(256) void k_onehot(const int* __restrict__ idxw,
                                                float* __restrict__ oh) {
  const int tid = threadIdx.x, bid = blockIdx.x;
#pragma unroll
  for (int r = 0; r < 16; ++r) {
    const int n = bid * 16 + r;
    const int id = idxw[n];
    float* row = oh + (size_t)n * NE;
    const int c = tid * 4;
    float2 v0, v1;
    v0.x = (c + 0 == id) ? 1.f : 0.f;
    v0.y = (c + 1 == id) ? 1.f : 0.f;
    v1.x = (c + 2 == id) ? 1.f : 0.f;
    v1.y = (c + 3 == id) ? 1.f : 0.f;
    *reinterpret_cast<float2*>(row + c)     = v0;
    *reinterpret_cast<float2*>(row + c + 2) = v1;
  }
}

// ---- deterministic loss total + perplexity ----
__global__ __launch_bounds__(256) void k_final(const float* __restrict__ lp,
                                               const unsigned int* __restrict__ counts,
                                               float* __restrict__ out) {
  __shared__ float red[256];
  const int t = threadIdx.x;
  red[t] = lp[t] + lp[t + 256];
  __syncthreads();
  for (int off = 128; off > 0; off >>= 1) {
    if (t < off) red[t] += red[t + off];
    __syncthreads();
  }
  if (t == 0) {
    float m = red[0] / 8388608.0f;
    out[LOSS_OFF] = m + 0.25f * m;
  }
  __syncthreads();
  float h = 0.f;
#pragma unroll
  for (int q = 0; q < 4; ++q) {
    int jj = t * 4 + q;
    float em = (float)counts[jj] * (1.0f / 32768.0f);
    h += em * logf(em + 1e-10f);
  }
  red[t] = h;
  __syncthreads();
  for (int off = 128; off > 0; off >>= 1) {
    if (t < off) red[t] += red[t + off];
    __syncthreads();
  }
  if (t == 0) out[PERP_OFF] = expf(-red[0]);
}

extern "C" void kernel_launch(void* const* d_in, const int* in_sizes, int n_in,
                              void* d_out, int out_size, void* d_ws, size_t ws_size,
                              hipStream_t stream) {
  const float* z    = (const float*)d_in[0];
  const float* mask = (const float*)d_in[1];
  const float* emb  = (const float*)d_in[2];
  float* out = (float*)d_out;
  char* ws = (char*)d_ws;
  int* idxw            = (int*)(ws + WS_IDX);
  unsigned int* counts = (unsigned int*)(ws + WS_CNT);
  float* lp            = (float*)(ws + WS_LP);
  float* e2            = (float*)(ws + WS_E2);
  float* z2            = (float*)(ws + WS_Z2);
  // argmin partials live in the one_hot region of d_out (overwritten later
  // by k_onehot; 1 MB << 134 MB)
  float* bd_ws = out + OH_OFF;
  int*   bi_ws = (int*)(out + OH_OFF) + NPTS * 4;

  hipMemsetAsync(counts, 0, NE * sizeof(unsigned int), stream);
  hipLaunchKernelGGL(k_e2, dim3(NE), dim3(64), 0, stream, emb, e2);
  hipLaunchKernelGGL(k_z2, dim3(512), dim3(256), 0, stream, z, z2);
  hipLaunchKernelGGL(k_dist, dim3(1024), dim3(256), 0, stream,
                     z, emb, e2, z2, bd_ws, bi_ws);
  hipLaunchKernelGGL(k_merge, dim3(NPTS / 256), dim3(256), 0, stream,
                     bd_ws, bi_ws, idxw, counts, out + IDX_OFF);
  hipLaunchKernelGGL(k_zq_loss, dim3(512), dim3(256), 0, stream,
                     z, emb, mask, idxw, out + ZQ_OFF, lp);
  hipLaunchKernelGGL(k_onehot, dim3(NPTS / 16), dim3(256), 0, stream,
                     idxw, out + OH_OFF);
  hipLaunchKernelGGL(k_final, dim3(1), dim3(256), 0, stream, lp, counts, out);
}

// Round 4
// 228.470 us; speedup vs baseline: 1.4610x; 1.1637x over previous
//
#include <hip/hip_runtime.h>

// Problem constants
constexpr int B_ = 32, C_ = 256, L_ = 1024, NE = 1024;
constexpr int NPTS = B_ * L_;            // 32768 points
// d_out flat float32 layout (reference return order)
constexpr long long LOSS_OFF = 0;
constexpr long long ZQ_OFF   = 1;                         // 8,388,608 elems
constexpr long long PERP_OFF = 1 + 8388608;               // 8388609
constexpr long long OH_OFF   = PERP_OFF + 1;              // 8388610
constexpr long long IDX_OFF  = OH_OFF + 33554432LL;       // 41943042
// workspace byte offsets (small stuff only; big scratch lives in one_hot region)
constexpr size_t WS_IDX = 0;            // int[32768]
constexpr size_t WS_CNT = 131072;       // uint[1024]
constexpr size_t WS_LP  = 135168;       // float[512]
constexpr size_t WS_E2  = 137216;       // float[1024]

constexpr float MARGIN = 7e-4f;         // >= 2*(fp16 dot err) + d-quantization slack

typedef _Float16 f16x8 __attribute__((ext_vector_type(8)));
typedef float    f32x4 __attribute__((ext_vector_type(4)));

__device__ inline unsigned fkey(float f) {
  unsigned u = __float_as_uint(f);
  return (u & 0x80000000u) ? ~u : (u | 0x80000000u);
}
__device__ inline float unfkey(unsigned k) {
  unsigned u = (k & 0x80000000u) ? (k ^ 0x80000000u) : ~k;
  return __uint_as_float(u);
}

// ---- e2[j] = sum_k emb[j][k]^2, fp64 accumulate -> fp32 (bit-matches R1-R3) ----
__global__ __launch_bounds__(64) void k_e2(const float* __restrict__ emb,
                                           float* __restrict__ e2) {
  const int j = blockIdx.x;
  const int t = threadIdx.x;
  const float* row = emb + (size_t)j * C_;
  double s = 0.0;
#pragma unroll
  for (int q = 0; q < 4; ++q) {
    float v = row[t + 64 * q];
    s += (double)v * (double)v;
  }
#pragma unroll
  for (int off = 32; off > 0; off >>= 1) s += __shfl_down(s, off);
  if (t == 0) e2[j] = (float)s;
}

// ---- codebook fp32 -> fp16 (RN), row-major [code][k] ----
__global__ __launch_bounds__(256) void k_ehl(const float* __restrict__ emb,
                                             _Float16* __restrict__ ehl) {
  const int i = blockIdx.x * 256 + threadIdx.x;   // 65536 float4 groups
  float4 v = reinterpret_cast<const float4*>(emb)[i];
  _Float16 h0 = (_Float16)v.x, h1 = (_Float16)v.y;
  _Float16 h2 = (_Float16)v.z, h3 = (_Float16)v.w;
  unsigned u0 = (unsigned)__builtin_bit_cast(unsigned short, h0) |
                ((unsigned)__builtin_bit_cast(unsigned short, h1) << 16);
  unsigned u1 = (unsigned)__builtin_bit_cast(unsigned short, h2) |
                ((unsigned)__builtin_bit_cast(unsigned short, h3) << 16);
  reinterpret_cast<uint2*>(ehl)[i] = make_uint2(u0, u1);
}

// ---- MFMA fp16 screen: per point, candidate codes with s <= min + MARGIN ----
// Block: 512 thr / 8 waves; tile 128 points x 1024 codes (4 chunks of 256).
// Wave (wr,wc): 64 pts x 64 codes = 4x4 tiles of mfma_f32_16x16x32_f16.
// A (z as f16) [128 pts][256 k] LDS-resident, XOR slot swizzle (conflict-free).
// B (ehl) [256 codes][128 k] staged per (chunk, k-half), reg-prefetched (T14).
__global__ __launch_bounds__(512, 2) void k_screen(const float* __restrict__ z,
                                                   const _Float16* __restrict__ ehl,
                                                   const float* __restrict__ e2g,
                                                   unsigned short* __restrict__ cand_codes,
                                                   unsigned* __restrict__ cand_cnt) {
  __shared__ _Float16 Az[128 * 256];     // 64 KB
  __shared__ _Float16 Bz[256 * 128];     // 64 KB
  __shared__ unsigned minkey[128];
  __shared__ unsigned ccnt[128];
  __shared__ unsigned short cand[128 * 32];   // 8 KB

  const int tid  = threadIdx.x;
  const int lane = tid & 63;
  const int wid  = tid >> 6;
  const int wr   = wid >> 2;          // 0..1 point half
  const int wc   = wid & 3;           // 0..3 code quarter (of chunk)
  const int l15  = lane & 15;
  const int lhi  = lane >> 4;         // 0..3
  const int n0   = blockIdx.x * 128;
  const int b    = blockIdx.x >> 3;
  const int l0   = (blockIdx.x & 7) << 7;

  const uint4* ehl4 = reinterpret_cast<const uint4*>(ehl);
  // B staging mapping: thread covers code = tid>>1, slots (tid&1)*8 + j
  const int stc   = tid >> 1;
  const int stso  = (tid & 1) * 8;

  uint4 nxt[8];
  // prologue: issue B(chunk0, khalf0) loads
#pragma unroll
  for (int j = 0; j < 8; ++j)
    nxt[j] = ehl4[(size_t)stc * 32 + stso + j];

  // A transpose+convert: z[b][k][l0+l'] fp32 -> Az[p][k] f16 swizzled
  {
    const float4* z4 = reinterpret_cast<const float4*>(z + (size_t)b * (C_ * L_) + l0);
    const int l4 = tid & 31;
    const int kp = tid >> 5;            // 0..15
#pragma unroll
    for (int rr = 0; rr < 8; ++rr) {
      const int k0 = rr * 32 + kp * 2;
      float4 a0 = z4[(size_t)k0 * (L_ / 4) + l4];
      float4 a1 = z4[(size_t)(k0 + 1) * (L_ / 4) + l4];
      const float av0[4] = {a0.x, a0.y, a0.z, a0.w};
      const float av1[4] = {a1.x, a1.y, a1.z, a1.w};
#pragma unroll
      for (int j = 0; j < 4; ++j) {
        _Float16 h0 = (_Float16)av0[j];
        _Float16 h1 = (_Float16)av1[j];
        unsigned pk = (unsigned)__builtin_bit_cast(unsigned short, h0) |
                      ((unsigned)__builtin_bit_cast(unsigned short, h1) << 16);
        const int p = l4 * 4 + j;
        const int slot = k0 >> 3;
        const int addr = p * 256 + ((slot ^ (p & 31)) << 3) + (k0 & 7);
        *reinterpret_cast<unsigned*>(&Az[addr]) = pk;
      }
    }
  }
  if (tid < 128) { minkey[tid] = 0xFFFFFFFFu; ccnt[tid] = 0u; }
  __syncthreads();
  // write B(0,0)
#pragma unroll
  for (int j = 0; j < 8; ++j) {
    const int swz = (stso + j) ^ (stc & 15);
    *reinterpret_cast<uint4*>(&Bz[stc * 128 + swz * 8]) = nxt[j];
  }
  __syncthreads();

  f32x4 acc[4][4];
#pragma unroll
  for (int i = 0; i < 4; ++i)
#pragma unroll
    for (int j = 0; j < 4; ++j) acc[i][j] = (f32x4){0.f, 0.f, 0.f, 0.f};

  for (int ph = 0; ph < 8; ++ph) {
    const int cc = ph >> 1;
    const int kh = ph & 1;
    // (a) prefetch next phase's B into regs
    if (ph < 7) {
      const int cc2 = (ph + 1) >> 1;
      const int kh2 = (ph + 1) & 1;
#pragma unroll
      for (int j = 0; j < 8; ++j)
        nxt[j] = ehl4[(size_t)(cc2 * 256 + stc) * 32 + kh2 * 16 + stso + j];
    }
    // (b) compute: 4 k-steps x 16 mfma
#pragma unroll
    for (int s = 0; s < 4; ++s) {
      const int slotA = kh * 16 + s * 4 + lhi;
      const int slotB = s * 4 + lhi;
      const int swzB  = slotB ^ l15;
      f16x8 bfr[4];
#pragma unroll
      for (int tj = 0; tj < 4; ++tj)
        bfr[tj] = *reinterpret_cast<const f16x8*>(
            &Bz[(wc * 64 + tj * 16 + l15) * 128 + swzB * 8]);
      f16x8 afr[4];
#pragma unroll
      for (int ti = 0; ti < 4; ++ti) {
        const int pA = wr * 64 + ti * 16 + l15;
        const int swzA = slotA ^ (((ti & 1) << 4) ^ l15);
        afr[ti] = *reinterpret_cast<const f16x8*>(&Az[pA * 256 + swzA * 8]);
      }
#pragma unroll
      for (int ti = 0; ti < 4; ++ti)
#pragma unroll
        for (int tj = 0; tj < 4; ++tj)
          acc[ti][tj] = __builtin_amdgcn_mfma_f32_16x16x32_f16(
              afr[ti], bfr[tj], acc[ti][tj], 0, 0, 0);
    }
    // (c) fold + candidate extraction at end of each code-chunk
    if (kh == 1) {
      float e2r[4];
#pragma unroll
      for (int tj = 0; tj < 4; ++tj)
        e2r[tj] = e2g[cc * 256 + wc * 64 + tj * 16 + l15];
      // per (ti, r): min over tj (regs) then over 16 lanes (codes)
#pragma unroll
      for (int ti = 0; ti < 4; ++ti) {
#pragma unroll
        for (int r = 0; r < 4; ++r) {
          float m = e2r[0] - 2.0f * acc[ti][0][r];
#pragma unroll
          for (int tj = 1; tj < 4; ++tj) {
            float v = e2r[tj] - 2.0f * acc[ti][tj][r];
            m = fminf(m, v);
          }
          m = fminf(m, __shfl_xor(m, 1));
          m = fminf(m, __shfl_xor(m, 2));
          m = fminf(m, __shfl_xor(m, 4));
          m = fminf(m, __shfl_xor(m, 8));
          if (l15 == 0) {
            const int p = wr * 64 + ti * 16 + lhi * 4 + r;
            atomicMin(&minkey[p], fkey(m));
          }
        }
      }
      __syncthreads();
      // extraction vs (running-min + margin): superset of final candidates
#pragma unroll
      for (int ti = 0; ti < 4; ++ti) {
#pragma unroll
        for (int r = 0; r < 4; ++r) {
          const int p = wr * 64 + ti * 16 + lhi * 4 + r;
          const float thr = unfkey(minkey[p]) + MARGIN;
#pragma unroll
          for (int tj = 0; tj < 4; ++tj) {
            float s = e2r[tj] - 2.0f * acc[ti][tj][r];
            if (s <= thr) {
              unsigned pos = atomicAdd(&ccnt[p], 1u);
              if (pos < 32u)
                cand[p * 32 + pos] = (unsigned short)(cc * 256 + wc * 64 + tj * 16 + l15);
            }
          }
        }
      }
      // reset acc for next chunk
#pragma unroll
      for (int i = 0; i < 4; ++i)
#pragma unroll
        for (int j = 0; j < 4; ++j) acc[i][j] = (f32x4){0.f, 0.f, 0.f, 0.f};
    }
    __syncthreads();
    // (d) write next phase's B
    if (ph < 7) {
#pragma unroll
      for (int j = 0; j < 8; ++j) {
        const int swz = (stso + j) ^ (stc & 15);
        *reinterpret_cast<uint4*>(&Bz[stc * 128 + swz * 8]) = nxt[j];
      }
    }
    __syncthreads();
  }

  if (tid < 128) {
    const int n = n0 + tid;
    cand_cnt[n] = ccnt[tid];
    const unsigned* src = reinterpret_cast<const unsigned*>(&cand[tid * 32]);
    unsigned* dst = reinterpret_cast<unsigned*>(cand_codes) + (size_t)n * 16;
#pragma unroll
    for (int q = 0; q < 16; ++q) dst[q] = src[q];
  }
}

// ---- exact re-rank: bit-identical fp32 chain for multi-candidate points ----
__global__ __launch_bounds__(256) void k_rerank(const float* __restrict__ z,
                                                const float* __restrict__ emb,
                                                const float* __restrict__ e2g,
                                                const unsigned short* __restrict__ cand_codes,
                                                const unsigned* __restrict__ cand_cnt,
                                                int* __restrict__ idxw,
                                                unsigned* __restrict__ counts,
                                                float* __restrict__ idx_out,
                                                unsigned* __restrict__ ovf) {
  const int n = blockIdx.x * 256 + threadIdx.x;
  const unsigned cnt = cand_cnt[n];
  int bi;
  if (cnt == 1u) {
    bi = cand_codes[(size_t)n * 32];
  } else if (cnt >= 2u && cnt <= 32u) {
    const int b = n >> 10, l = n & 1023;
    const float* zc = z + (size_t)b * (C_ * L_) + l;
    double zsq = 0.0;
#pragma unroll 8
    for (int k = 0; k < 256; ++k) {
      float v = zc[(size_t)k * L_];
      zsq += (double)v * (double)v;
    }
    const float z2 = (float)zsq;
    float bd = 3.4e38f;
    bi = 0x7fffffff;
    for (unsigned q = 0; q < cnt; ++q) {
      const int c = cand_codes[(size_t)n * 32 + q];
      const float* er = emb + (size_t)c * C_;
      float acc = 0.f;
#pragma unroll 8
      for (int k = 0; k < 256; ++k) acc = fmaf(zc[(size_t)k * L_], er[k], acc);
      const float d = (z2 + e2g[c]) - 2.0f * acc;   // numpy op order
      if (d < bd || (d == bd && c < bi)) { bd = d; bi = c; }
    }
  } else {  // cnt==0 (impossible) or overflow: full-scan fallback
    unsigned pos = atomicAdd(ovf, 1u);
    ovf[1 + pos] = (unsigned)n;
    return;
  }
  idxw[n] = bi;
  idx_out[n] = (float)bi;
  atomicAdd(&counts[bi], 1u);
}

// ---- overflow fallback: exact full scan of all 1024 codes (normally 0 work) ----
__global__ __launch_bounds__(256) void k_ovf(const float* __restrict__ z,
                                             const float* __restrict__ emb,
                                             const float* __restrict__ e2g,
                                             const unsigned* __restrict__ ovf,
                                             int* __restrict__ idxw,
                                             unsigned* __restrict__ counts,
                                             float* __restrict__ idx_out) {
  __shared__ float zs[256];
  __shared__ float rdd[256];
  __shared__ int rdi[256];
  const unsigned tot = ovf[0];
  const int tid = threadIdx.x;
  for (unsigned i = blockIdx.x; i < tot; i += gridDim.x) {
    const int n = (int)ovf[1 + i];
    const int b = n >> 10, l = n & 1023;
    zs[tid] = z[(size_t)b * (C_ * L_) + (size_t)tid * L_ + l];
    __syncthreads();
    double zsq = 0.0;
    for (int k = 0; k < 256; ++k) zsq += (double)zs[k] * (double)zs[k];
    const float z2 = (float)zsq;
    float bd = 3.4e38f;
    int bi = 0x7fffffff;
    for (int c = tid * 4; c < tid * 4 + 4; ++c) {
      const float* er = emb + (size_t)c * C_;
      float acc = 0.f;
      for (int k = 0; k < 256; ++k) acc = fmaf(zs[k], er[k], acc);
      const float d = (z2 + e2g[c]) - 2.0f * acc;
      if (d < bd || (d == bd && c < bi)) { bd = d; bi = c; }
    }
    rdd[tid] = bd; rdi[tid] = bi;
    __syncthreads();
    for (int off = 128; off > 0; off >>= 1) {
      if (tid < off) {
        if (rdd[tid + off] < rdd[tid] ||
            (rdd[tid + off] == rdd[tid] && rdi[tid + off] < rdi[tid])) {
          rdd[tid] = rdd[tid + off]; rdi[tid] = rdi[tid + off];
        }
      }
      __syncthreads();
    }
    if (tid == 0) {
      idxw[n] = rdi[0];
      idx_out[n] = (float)rdi[0];
      atomicAdd(&counts[rdi[0]], 1u);
    }
    __syncthreads();
  }
}

// ---- fused gather (z_q straight-through) + masked loss partials ----
__global__ __launch_bounds__(256) void k_zq_loss(const float* __restrict__ z,
                                                 const float* __restrict__ emb,
                                                 const float* __restrict__ mask,
                                                 const int* __restrict__ idxw,
                                                 float* __restrict__ zq_out,
                                                 float* __restrict__ lp) {
  __shared__ float eq[256][66];
  __shared__ float red[256];
  const int tid = threadIdx.x, bid = blockIdx.x;
  const int b = bid >> 4, l0 = (bid & 15) << 6, n0 = bid << 6;
  {
    const int r  = tid >> 2;
    const int kq = tid & 3;
    const int id = idxw[n0 + r];
    const float4* e4 = reinterpret_cast<const float4*>(emb + (size_t)id * C_);
#pragma unroll
    for (int rep = 0; rep < 16; ++rep) {
      int c4 = rep * 4 + kq;
      float4 v = e4[c4];
      eq[c4 * 4 + 0][r] = v.x;
      eq[c4 * 4 + 1][r] = v.y;
      eq[c4 * 4 + 2][r] = v.z;
      eq[c4 * 4 + 3][r] = v.w;
    }
  }
  __syncthreads();
  const int lq = tid & 63, cg = tid >> 6;
  const float m = mask[b * L_ + l0 + lq];
  const size_t zbase = (size_t)b * C_ * L_ + l0 + lq;
  float s = 0.f;
#pragma unroll 4
  for (int ci = 0; ci < 64; ++ci) {
    int c = cg * 64 + ci;
    float zv = z[zbase + (size_t)c * L_];
    float q  = eq[c][lq];
    float diff = q - zv;
    zq_out[zbase + (size_t)c * L_] = zv + diff;
    float t = diff * m;
    s = fmaf(t, t, s);
  }
  red[tid] = s;
  __syncthreads();
  for (int off = 128; off > 0; off >>= 1) {
    if (tid < off) red[tid] += red[tid + off];
    __syncthreads();
  }
  if (tid == 0) lp[bid] = red[0];
}

// ---- one_hot: single pass, values on the fly ----
__global__ __launch_bounds__(256) void k_onehot(const int* __restrict__ idxw,
                                                float* __restrict__ oh) {
  const int tid = threadIdx.x, bid = blockIdx.x;
#pragma unroll
  for (int r = 0; r < 16; ++r) {
    const int n = bid * 16 + r;
    const int id = idxw[n];
    float* row = oh + (size_t)n * NE;
    const int c = tid * 4;
    float2 v0, v1;
    v0.x = (c + 0 == id) ? 1.f : 0.f;
    v0.y = (c + 1 == id) ? 1.f : 0.f;
    v1.x = (c + 2 == id) ? 1.f : 0.f;
    v1.y = (c + 3 == id) ? 1.f : 0.f;
    *reinterpret_cast<float2*>(row + c)     = v0;
    *reinterpret_cast<float2*>(row + c + 2) = v1;
  }
}

// ---- deterministic loss total + perplexity ----
__global__ __launch_bounds__(256) void k_final(const float* __restrict__ lp,
                                               const unsigned int* __restrict__ counts,
                                               float* __restrict__ out) {
  __shared__ float red[256];
  const int t = threadIdx.x;
  red[t] = lp[t] + lp[t + 256];
  __syncthreads();
  for (int off = 128; off > 0; off >>= 1) {
    if (t < off) red[t] += red[t + off];
    __syncthreads();
  }
  if (t == 0) {
    float m = red[0] / 8388608.0f;
    out[LOSS_OFF] = m + 0.25f * m;
  }
  __syncthreads();
  float h = 0.f;
#pragma unroll
  for (int q = 0; q < 4; ++q) {
    int jj = t * 4 + q;
    float em = (float)counts[jj] * (1.0f / 32768.0f);
    h += em * logf(em + 1e-10f);
  }
  red[t] = h;
  __syncthreads();
  for (int off = 128; off > 0; off >>= 1) {
    if (t < off) red[t] += red[t + off];
    __syncthreads();
  }
  if (t == 0) out[PERP_OFF] = expf(-red[0]);
}

extern "C" void kernel_launch(void* const* d_in, const int* in_sizes, int n_in,
                              void* d_out, int out_size, void* d_ws, size_t ws_size,
                              hipStream_t stream) {
  const float* z    = (const float*)d_in[0];
  const float* mask = (const float*)d_in[1];
  const float* emb  = (const float*)d_in[2];
  float* out = (float*)d_out;
  char* ws = (char*)d_ws;
  int* idxw            = (int*)(ws + WS_IDX);
  unsigned int* counts = (unsigned int*)(ws + WS_CNT);
  float* lp            = (float*)(ws + WS_LP);
  float* e2            = (float*)(ws + WS_E2);

  // big scratch inside the one_hot output region (overwritten by k_onehot later)
  uintptr_t sp = (uintptr_t)(out + OH_OFF);
  sp = (sp + 15) & ~(uintptr_t)15;
  _Float16* ehl              = (_Float16*)sp;                              // 512 KB
  unsigned short* cand_codes = (unsigned short*)(sp + 524288);             // 2 MB
  unsigned* cand_cnt         = (unsigned*)(sp + 524288 + 2097152);         // 128 KB
  unsigned* ovf              = (unsigned*)(sp + 524288 + 2097152 + 131072);// 132 KB

  hipMemsetAsync(counts, 0, NE * sizeof(unsigned int), stream);
  hipMemsetAsync(ovf, 0, sizeof(unsigned int), stream);
  hipLaunchKernelGGL(k_e2, dim3(NE), dim3(64), 0, stream, emb, e2);
  hipLaunchKernelGGL(k_ehl, dim3(256), dim3(256), 0, stream, emb, ehl);
  hipLaunchKernelGGL(k_screen, dim3(256), dim3(512), 0, stream,
                     z, ehl, e2, cand_codes, cand_cnt);
  hipLaunchKernelGGL(k_rerank, dim3(NPTS / 256), dim3(256), 0, stream,
                     z, emb, e2, cand_codes, cand_cnt, idxw, counts,
                     out + IDX_OFF, ovf);
  hipLaunchKernelGGL(k_ovf, dim3(64), dim3(256), 0, stream,
                     z, emb, e2, ovf, idxw, counts, out + IDX_OFF);
  hipLaunchKernelGGL(k_zq_loss, dim3(512), dim3(256), 0, stream,
                     z, emb, mask, idxw, out + ZQ_OFF, lp);
  hipLaunchKernelGGL(k_onehot, dim3(NPTS / 16), dim3(256), 0, stream,
                     idxw, out + OH_OFF);
  hipLaunchKernelGGL(k_final, dim3(1), dim3(256), 0, stream, lp, counts, out);
}

// Round 5
// 157.488 us; speedup vs baseline: 2.1195x; 1.4507x over previous
//
#include <hip/hip_runtime.h>

// Problem constants
constexpr int B_ = 32, C_ = 256, L_ = 1024, NE = 1024;
constexpr int NPTS = B_ * L_;            // 32768 points
// d_out flat float32 layout (reference return order)
constexpr long long LOSS_OFF = 0;
constexpr long long ZQ_OFF   = 1;                         // 8,388,608 elems
constexpr long long PERP_OFF = 1 + 8388608;               // 8388609
constexpr long long OH_OFF   = PERP_OFF + 1;              // 8388610
constexpr long long IDX_OFF  = OH_OFF + 33554432LL;       // 41943042
// workspace byte offsets (small stuff only; big scratch lives in one_hot region)
constexpr size_t WS_IDX = 0;            // int[32768]
constexpr size_t WS_CNT = 131072;       // uint[1024]
constexpr size_t WS_LP  = 135168;       // float[512]
constexpr size_t WS_E2  = 137216;       // float[1024]

constexpr float MARGIN = 7e-4f;         // >= 2*(fp16 dot err) + d-quantization slack

typedef _Float16 f16x8 __attribute__((ext_vector_type(8)));
typedef float    f32x4 __attribute__((ext_vector_type(4)));

__device__ inline unsigned fkey(float f) {
  unsigned u = __float_as_uint(f);
  return (u & 0x80000000u) ? ~u : (u | 0x80000000u);
}
__device__ inline float unfkey(unsigned k) {
  unsigned u = (k & 0x80000000u) ? (k ^ 0x80000000u) : ~k;
  return __uint_as_float(u);
}

// ---- e2[j] = sum_k emb[j][k]^2, fp64 accumulate -> fp32 (bit-matches R1-R4) ----
__global__ __launch_bounds__(64) void k_e2(const float* __restrict__ emb,
                                           float* __restrict__ e2) {
  const int j = blockIdx.x;
  const int t = threadIdx.x;
  const float* row = emb + (size_t)j * C_;
  double s = 0.0;
#pragma unroll
  for (int q = 0; q < 4; ++q) {
    float v = row[t + 64 * q];
    s += (double)v * (double)v;
  }
#pragma unroll
  for (int off = 32; off > 0; off >>= 1) s += __shfl_down(s, off);
  if (t == 0) e2[j] = (float)s;
}

// ---- codebook fp32 -> fp16 (RN), row-major [code][k] ----
__global__ __launch_bounds__(256) void k_ehl(const float* __restrict__ emb,
                                             _Float16* __restrict__ ehl) {
  const int i = blockIdx.x * 256 + threadIdx.x;   // 65536 float4 groups
  float4 v = reinterpret_cast<const float4*>(emb)[i];
  _Float16 h0 = (_Float16)v.x, h1 = (_Float16)v.y;
  _Float16 h2 = (_Float16)v.z, h3 = (_Float16)v.w;
  unsigned u0 = (unsigned)__builtin_bit_cast(unsigned short, h0) |
                ((unsigned)__builtin_bit_cast(unsigned short, h1) << 16);
  unsigned u1 = (unsigned)__builtin_bit_cast(unsigned short, h2) |
                ((unsigned)__builtin_bit_cast(unsigned short, h3) << 16);
  reinterpret_cast<uint2*>(ehl)[i] = make_uint2(u0, u1);
}

// ---- MFMA fp16 screen: per point, candidate codes with s <= min + MARGIN ----
// (unchanged from R4 — verified absmax 0.0)
__global__ __launch_bounds__(512, 2) void k_screen(const float* __restrict__ z,
                                                   const _Float16* __restrict__ ehl,
                                                   const float* __restrict__ e2g,
                                                   unsigned short* __restrict__ cand_codes,
                                                   unsigned* __restrict__ cand_cnt) {
  __shared__ _Float16 Az[128 * 256];     // 64 KB
  __shared__ _Float16 Bz[256 * 128];     // 64 KB
  __shared__ unsigned minkey[128];
  __shared__ unsigned ccnt[128];
  __shared__ unsigned short cand[128 * 32];   // 8 KB

  const int tid  = threadIdx.x;
  const int lane = tid & 63;
  const int wid  = tid >> 6;
  const int wr   = wid >> 2;
  const int wc   = wid & 3;
  const int l15  = lane & 15;
  const int lhi  = lane >> 4;
  const int n0   = blockIdx.x * 128;
  const int b    = blockIdx.x >> 3;
  const int l0   = (blockIdx.x & 7) << 7;

  const uint4* ehl4 = reinterpret_cast<const uint4*>(ehl);
  const int stc   = tid >> 1;
  const int stso  = (tid & 1) * 8;

  uint4 nxt[8];
#pragma unroll
  for (int j = 0; j < 8; ++j)
    nxt[j] = ehl4[(size_t)stc * 32 + stso + j];

  {
    const float4* z4 = reinterpret_cast<const float4*>(z + (size_t)b * (C_ * L_) + l0);
    const int l4 = tid & 31;
    const int kp = tid >> 5;
#pragma unroll
    for (int rr = 0; rr < 8; ++rr) {
      const int k0 = rr * 32 + kp * 2;
      float4 a0 = z4[(size_t)k0 * (L_ / 4) + l4];
      float4 a1 = z4[(size_t)(k0 + 1) * (L_ / 4) + l4];
      const float av0[4] = {a0.x, a0.y, a0.z, a0.w};
      const float av1[4] = {a1.x, a1.y, a1.z, a1.w};
#pragma unroll
      for (int j = 0; j < 4; ++j) {
        _Float16 h0 = (_Float16)av0[j];
        _Float16 h1 = (_Float16)av1[j];
        unsigned pk = (unsigned)__builtin_bit_cast(unsigned short, h0) |
                      ((unsigned)__builtin_bit_cast(unsigned short, h1) << 16);
        const int p = l4 * 4 + j;
        const int slot = k0 >> 3;
        const int addr = p * 256 + ((slot ^ (p & 31)) << 3) + (k0 & 7);
        *reinterpret_cast<unsigned*>(&Az[addr]) = pk;
      }
    }
  }
  if (tid < 128) { minkey[tid] = 0xFFFFFFFFu; ccnt[tid] = 0u; }
  __syncthreads();
#pragma unroll
  for (int j = 0; j < 8; ++j) {
    const int swz = (stso + j) ^ (stc & 15);
    *reinterpret_cast<uint4*>(&Bz[stc * 128 + swz * 8]) = nxt[j];
  }
  __syncthreads();

  f32x4 acc[4][4];
#pragma unroll
  for (int i = 0; i < 4; ++i)
#pragma unroll
    for (int j = 0; j < 4; ++j) acc[i][j] = (f32x4){0.f, 0.f, 0.f, 0.f};

  for (int ph = 0; ph < 8; ++ph) {
    const int cc = ph >> 1;
    const int kh = ph & 1;
    if (ph < 7) {
      const int cc2 = (ph + 1) >> 1;
      const int kh2 = (ph + 1) & 1;
#pragma unroll
      for (int j = 0; j < 8; ++j)
        nxt[j] = ehl4[(size_t)(cc2 * 256 + stc) * 32 + kh2 * 16 + stso + j];
    }
#pragma unroll
    for (int s = 0; s < 4; ++s) {
      const int slotA = kh * 16 + s * 4 + lhi;
      const int slotB = s * 4 + lhi;
      const int swzB  = slotB ^ l15;
      f16x8 bfr[4];
#pragma unroll
      for (int tj = 0; tj < 4; ++tj)
        bfr[tj] = *reinterpret_cast<const f16x8*>(
            &Bz[(wc * 64 + tj * 16 + l15) * 128 + swzB * 8]);
      f16x8 afr[4];
#pragma unroll
      for (int ti = 0; ti < 4; ++ti) {
        const int pA = wr * 64 + ti * 16 + l15;
        const int swzA = slotA ^ (((ti & 1) << 4) ^ l15);
        afr[ti] = *reinterpret_cast<const f16x8*>(&Az[pA * 256 + swzA * 8]);
      }
#pragma unroll
      for (int ti = 0; ti < 4; ++ti)
#pragma unroll
        for (int tj = 0; tj < 4; ++tj)
          acc[ti][tj] = __builtin_amdgcn_mfma_f32_16x16x32_f16(
              afr[ti], bfr[tj], acc[ti][tj], 0, 0, 0);
    }
    if (kh == 1) {
      float e2r[4];
#pragma unroll
      for (int tj = 0; tj < 4; ++tj)
        e2r[tj] = e2g[cc * 256 + wc * 64 + tj * 16 + l15];
#pragma unroll
      for (int ti = 0; ti < 4; ++ti) {
#pragma unroll
        for (int r = 0; r < 4; ++r) {
          float m = e2r[0] - 2.0f * acc[ti][0][r];
#pragma unroll
          for (int tj = 1; tj < 4; ++tj) {
            float v = e2r[tj] - 2.0f * acc[ti][tj][r];
            m = fminf(m, v);
          }
          m = fminf(m, __shfl_xor(m, 1));
          m = fminf(m, __shfl_xor(m, 2));
          m = fminf(m, __shfl_xor(m, 4));
          m = fminf(m, __shfl_xor(m, 8));
          if (l15 == 0) {
            const int p = wr * 64 + ti * 16 + lhi * 4 + r;
            atomicMin(&minkey[p], fkey(m));
          }
        }
      }
      __syncthreads();
#pragma unroll
      for (int ti = 0; ti < 4; ++ti) {
#pragma unroll
        for (int r = 0; r < 4; ++r) {
          const int p = wr * 64 + ti * 16 + lhi * 4 + r;
          const float thr = unfkey(minkey[p]) + MARGIN;
#pragma unroll
          for (int tj = 0; tj < 4; ++tj) {
            float s = e2r[tj] - 2.0f * acc[ti][tj][r];
            if (s <= thr) {
              unsigned pos = atomicAdd(&ccnt[p], 1u);
              if (pos < 32u)
                cand[p * 32 + pos] = (unsigned short)(cc * 256 + wc * 64 + tj * 16 + l15);
            }
          }
        }
      }
#pragma unroll
      for (int i = 0; i < 4; ++i)
#pragma unroll
        for (int j = 0; j < 4; ++j) acc[i][j] = (f32x4){0.f, 0.f, 0.f, 0.f};
    }
    __syncthreads();
    if (ph < 7) {
#pragma unroll
      for (int j = 0; j < 8; ++j) {
        const int swz = (stso + j) ^ (stc & 15);
        *reinterpret_cast<uint4*>(&Bz[stc * 128 + swz * 8]) = nxt[j];
      }
    }
    __syncthreads();
  }

  if (tid < 128) {
    const int n = n0 + tid;
    cand_cnt[n] = ccnt[tid];
    const unsigned* src = reinterpret_cast<const unsigned*>(&cand[tid * 32]);
    unsigned* dst = reinterpret_cast<unsigned*>(cand_codes) + (size_t)n * 16;
#pragma unroll
    for (int q = 0; q < 16; ++q) dst[q] = src[q];
  }
}

// ---- exact re-rank, TILED: 64 points/block, z staged in LDS (coalesced) ----
// Pair (point, candidate) work distributed across all 256 threads; dot chain
// is the bit-identical sequential-k fmaf order that has passed R1-R4.
__global__ __launch_bounds__(256, 2) void k_rerank(const float* __restrict__ z,
                                                   const float* __restrict__ emb,
                                                   const float* __restrict__ e2g,
                                                   const unsigned short* __restrict__ cand_codes,
                                                   const unsigned* __restrict__ cand_cnt,
                                                   int* __restrict__ idxw,
                                                   unsigned* __restrict__ counts,
                                                   float* __restrict__ idx_out,
                                                   unsigned* __restrict__ ovf) {
  __shared__ float zs[256][68];           // 69.6 KB
  __shared__ float z2s[64];
  __shared__ unsigned short poff[65];
  __shared__ unsigned char  pcnt[64];
  __shared__ unsigned short ppt[1024];
  __shared__ unsigned char  pq[1024];
  __shared__ float pd[1024];
  __shared__ int ptot;

  const int tid = threadIdx.x, bid = blockIdx.x;
  const int b = bid >> 4, l0 = (bid & 15) << 6, n0 = bid << 6;

  // stage zs[k][l'] = z[b][k][l0+l']  (float4 coalesced along l)
  {
    const float4* z4 = reinterpret_cast<const float4*>(z + (size_t)b * C_ * L_ + l0);
    const int l4 = tid & 15, kk = tid >> 4;
#pragma unroll
    for (int rep = 0; rep < 16; ++rep) {
      int k = rep * 16 + kk;
      float4 v = z4[(size_t)k * (L_ / 4) + l4];
      *reinterpret_cast<float4*>(&zs[k][l4 * 4]) = v;
    }
  }
  if (tid == 0) ptot = 0;
  __syncthreads();

  // classify points; cnt==1 resolves immediately
  if (tid < 64) {
    const int n = n0 + tid;
    const unsigned cnt = cand_cnt[n];
    pcnt[tid] = (cnt >= 2u && cnt <= 32u) ? (unsigned char)cnt : 0;
    if (cnt == 1u) {
      const int biv = cand_codes[(size_t)n * 32];
      idxw[n] = biv;
      idx_out[n] = (float)biv;
      atomicAdd(&counts[biv], 1u);
    } else if (cnt == 0u || cnt > 32u) {
      unsigned pos = atomicAdd(ovf, 1u);
      ovf[1 + pos] = (unsigned)n;
    }
  }
  __syncthreads();
  if (tid == 0) {
    unsigned s = 0;
    for (int p = 0; p < 64; ++p) { poff[p] = (unsigned short)s; s += pcnt[p]; }
    ptot = (int)s;
  }
  __syncthreads();
  const int P = ptot;
  if (P == 0) return;
  if (P > 1024) {  // astronomically unlikely: defer multi-cand points to k_ovf
    if (tid < 64 && pcnt[tid]) {
      unsigned pos = atomicAdd(ovf, 1u);
      ovf[1 + pos] = (unsigned)(n0 + tid);
    }
    return;
  }

  // z2 (fp64 chain, bit-matches R1-R4) + pair list fill
  if (tid < 64 && pcnt[tid]) {
    double s = 0.0;
#pragma unroll 8
    for (int k = 0; k < 256; ++k) {
      float v = zs[k][tid];
      s += (double)v * (double)v;
    }
    z2s[tid] = (float)s;
    const int o = poff[tid];
    for (int q = 0; q < (int)pcnt[tid]; ++q) {
      ppt[o + q] = (unsigned short)tid;
      pq[o + q] = (unsigned char)q;
    }
  }
  __syncthreads();

  // exact pair distances (sequential k fmaf, float4 emb row loads, L2-hot)
  for (int i = tid; i < P; i += 256) {
    const int p = ppt[i];
    const int n = n0 + p;
    const int c = cand_codes[(size_t)n * 32 + pq[i]];
    const float4* er = reinterpret_cast<const float4*>(emb + (size_t)c * C_);
    float acc = 0.f;
#pragma unroll 4
    for (int k4 = 0; k4 < 64; ++k4) {
      float4 e = er[k4];
      acc = fmaf(zs[k4 * 4 + 0][p], e.x, acc);
      acc = fmaf(zs[k4 * 4 + 1][p], e.y, acc);
      acc = fmaf(zs[k4 * 4 + 2][p], e.z, acc);
      acc = fmaf(zs[k4 * 4 + 3][p], e.w, acc);
    }
    pd[i] = (z2s[p] + e2g[c]) - 2.0f * acc;   // numpy op order
  }
  __syncthreads();

  // winner per point (candidate list unordered: tie -> lower code)
  if (tid < 64 && pcnt[tid]) {
    const int n = n0 + tid;
    float bd = 3.4e38f;
    int biv = 0x7fffffff;
    for (int q = 0; q < (int)pcnt[tid]; ++q) {
      const int i = poff[tid] + q;
      const float d = pd[i];
      const int c = cand_codes[(size_t)n * 32 + pq[i]];
      if (d < bd || (d == bd && c < biv)) { bd = d; biv = c; }
    }
    idxw[n] = biv;
    idx_out[n] = (float)biv;
    atomicAdd(&counts[biv], 1u);
  }
}

// ---- overflow fallback: exact full scan of all 1024 codes (normally 0 work) ----
__global__ __launch_bounds__(256) void k_ovf(const float* __restrict__ z,
                                             const float* __restrict__ emb,
                                             const float* __restrict__ e2g,
                                             const unsigned* __restrict__ ovf,
                                             int* __restrict__ idxw,
                                             unsigned* __restrict__ counts,
                                             float* __restrict__ idx_out) {
  __shared__ float zs[256];
  __shared__ float rdd[256];
  __shared__ int rdi[256];
  const unsigned tot = ovf[0];
  const int tid = threadIdx.x;
  for (unsigned i = blockIdx.x; i < tot; i += gridDim.x) {
    const int n = (int)ovf[1 + i];
    const int b = n >> 10, l = n & 1023;
    zs[tid] = z[(size_t)b * (C_ * L_) + (size_t)tid * L_ + l];
    __syncthreads();
    double zsq = 0.0;
    for (int k = 0; k < 256; ++k) zsq += (double)zs[k] * (double)zs[k];
    const float z2 = (float)zsq;
    float bd = 3.4e38f;
    int bi = 0x7fffffff;
    for (int c = tid * 4; c < tid * 4 + 4; ++c) {
      const float* er = emb + (size_t)c * C_;
      float acc = 0.f;
      for (int k = 0; k < 256; ++k) acc = fmaf(zs[k], er[k], acc);
      const float d = (z2 + e2g[c]) - 2.0f * acc;
      if (d < bd || (d == bd && c < bi)) { bd = d; bi = c; }
    }
    rdd[tid] = bd; rdi[tid] = bi;
    __syncthreads();
    for (int off = 128; off > 0; off >>= 1) {
      if (tid < off) {
        if (rdd[tid + off] < rdd[tid] ||
            (rdd[tid + off] == rdd[tid] && rdi[tid + off] < rdi[tid])) {
          rdd[tid] = rdd[tid + off]; rdi[tid] = rdi[tid + off];
        }
      }
      __syncthreads();
    }
    if (tid == 0) {
      idxw[n] = rdi[0];
      idx_out[n] = (float)rdi[0];
      atomicAdd(&counts[rdi[0]], 1u);
    }
    __syncthreads();
  }
}

// ---- fused gather (z_q straight-through) + masked loss partials ----
__global__ __launch_bounds__(256) void k_zq_loss(const float* __restrict__ z,
                                                 const float* __restrict__ emb,
                                                 const float* __restrict__ mask,
                                                 const int* __restrict__ idxw,
                                                 float* __restrict__ zq_out,
                                                 float* __restrict__ lp) {
  __shared__ float eq[256][66];
  __shared__ float red[256];
  const int tid = threadIdx.x, bid = blockIdx.x;
  const int b = bid >> 4, l0 = (bid & 15) << 6, n0 = bid << 6;
  {
    const int r  = tid >> 2;
    const int kq = tid & 3;
    const int id = idxw[n0 + r];
    const float4* e4 = reinterpret_cast<const float4*>(emb + (size_t)id * C_);
#pragma unroll
    for (int rep = 0; rep < 16; ++rep) {
      int c4 = rep * 4 + kq;
      float4 v = e4[c4];
      eq[c4 * 4 + 0][r] = v.x;
      eq[c4 * 4 + 1][r] = v.y;
      eq[c4 * 4 + 2][r] = v.z;
      eq[c4 * 4 + 3][r] = v.w;
    }
  }
  __syncthreads();
  const int lq = tid & 63, cg = tid >> 6;
  const float m = mask[b * L_ + l0 + lq];
  const size_t zbase = (size_t)b * C_ * L_ + l0 + lq;
  float s = 0.f;
#pragma unroll 4
  for (int ci = 0; ci < 64; ++ci) {
    int c = cg * 64 + ci;
    float zv = z[zbase + (size_t)c * L_];
    float q  = eq[c][lq];
    float diff = q - zv;
    zq_out[zbase + (size_t)c * L_] = zv + diff;
    float t = diff * m;
    s = fmaf(t, t, s);
  }
  red[tid] = s;
  __syncthreads();
  for (int off = 128; off > 0; off >>= 1) {
    if (tid < off) red[tid] += red[tid + off];
    __syncthreads();
  }
  if (tid == 0) lp[bid] = red[0];
}

// ---- one_hot: single pass, values on the fly ----
__global__ __launch_bounds__(256) void k_onehot(const int* __restrict__ idxw,
                                                float* __restrict__ oh) {
  const int tid = threadIdx.x, bid = blockIdx.x;
#pragma unroll
  for (int r = 0; r < 16; ++r) {
    const int n = bid * 16 + r;
    const int id = idxw[n];
    float* row = oh + (size_t)n * NE;
    const int c = tid * 4;
    float2 v0, v1;
    v0.x = (c + 0 == id) ? 1.f : 0.f;
    v0.y = (c + 1 == id) ? 1.f : 0.f;
    v1.x = (c + 2 == id) ? 1.f : 0.f;
    v1.y = (c + 3 == id) ? 1.f : 0.f;
    *reinterpret_cast<float2*>(row + c)     = v0;
    *reinterpret_cast<float2*>(row + c + 2) = v1;
  }
}

// ---- deterministic loss total + perplexity ----
__global__ __launch_bounds__(256) void k_final(const float* __restrict__ lp,
                                               const unsigned int* __restrict__ counts,
                                               float* __restrict__ out) {
  __shared__ float red[256];
  const int t = threadIdx.x;
  red[t] = lp[t] + lp[t + 256];
  __syncthreads();
  for (int off = 128; off > 0; off >>= 1) {
    if (t < off) red[t] += red[t + off];
    __syncthreads();
  }
  if (t == 0) {
    float m = red[0] / 8388608.0f;
    out[LOSS_OFF] = m + 0.25f * m;
  }
  __syncthreads();
  float h = 0.f;
#pragma unroll
  for (int q = 0; q < 4; ++q) {
    int jj = t * 4 + q;
    float em = (float)counts[jj] * (1.0f / 32768.0f);
    h += em * logf(em + 1e-10f);
  }
  red[t] = h;
  __syncthreads();
  for (int off = 128; off > 0; off >>= 1) {
    if (t < off) red[t] += red[t + off];
    __syncthreads();
  }
  if (t == 0) out[PERP_OFF] = expf(-red[0]);
}

extern "C" void kernel_launch(void* const* d_in, const int* in_sizes, int n_in,
                              void* d_out, int out_size, void* d_ws, size_t ws_size,
                              hipStream_t stream) {
  const float* z    = (const float*)d_in[0];
  const float* mask = (const float*)d_in[1];
  const float* emb  = (const float*)d_in[2];
  float* out = (float*)d_out;
  char* ws = (char*)d_ws;
  int* idxw            = (int*)(ws + WS_IDX);
  unsigned int* counts = (unsigned int*)(ws + WS_CNT);
  float* lp            = (float*)(ws + WS_LP);
  float* e2            = (float*)(ws + WS_E2);

  // big scratch inside the one_hot output region (overwritten by k_onehot later)
  uintptr_t sp = (uintptr_t)(out + OH_OFF);
  sp = (sp + 15) & ~(uintptr_t)15;
  _Float16* ehl              = (_Float16*)sp;                              // 512 KB
  unsigned short* cand_codes = (unsigned short*)(sp + 524288);             // 2 MB
  unsigned* cand_cnt         = (unsigned*)(sp + 524288 + 2097152);         // 128 KB
  unsigned* ovf              = (unsigned*)(sp + 524288 + 2097152 + 131072);// 132 KB

  hipMemsetAsync(counts, 0, NE * sizeof(unsigned int), stream);
  hipMemsetAsync(ovf, 0, sizeof(unsigned int), stream);
  hipLaunchKernelGGL(k_e2, dim3(NE), dim3(64), 0, stream, emb, e2);
  hipLaunchKernelGGL(k_ehl, dim3(256), dim3(256), 0, stream, emb, ehl);
  hipLaunchKernelGGL(k_screen, dim3(256), dim3(512), 0, stream,
                     z, ehl, e2, cand_codes, cand_cnt);
  hipLaunchKernelGGL(k_rerank, dim3(512), dim3(256), 0, stream,
                     z, emb, e2, cand_codes, cand_cnt, idxw, counts,
                     out + IDX_OFF, ovf);
  hipLaunchKernelGGL(k_ovf, dim3(64), dim3(256), 0, stream,
                     z, emb, e2, ovf, idxw, counts, out + IDX_OFF);
  hipLaunchKernelGGL(k_zq_loss, dim3(512), dim3(256), 0, stream,
                     z, emb, mask, idxw, out + ZQ_OFF, lp);
  hipLaunchKernelGGL(k_onehot, dim3(NPTS / 16), dim3(256), 0, stream,
                     idxw, out + OH_OFF);
  hipLaunchKernelGGL(k_final, dim3(1), dim3(256), 0, stream, lp, counts, out);
}

// Round 6
// 130.489 us; speedup vs baseline: 2.5581x; 1.2069x over previous
//
#include <hip/hip_runtime.h>

// Problem constants
constexpr int B_ = 32, C_ = 256, L_ = 1024, NE = 1024;
constexpr int NPTS = B_ * L_;            // 32768 points
// d_out flat float32 layout (reference return order)
constexpr long long LOSS_OFF = 0;
constexpr long long ZQ_OFF   = 1;                         // 8,388,608 elems
constexpr long long PERP_OFF = 1 + 8388608;               // 8388609
constexpr long long OH_OFF   = PERP_OFF + 1;              // 8388610
constexpr long long IDX_OFF  = OH_OFF + 33554432LL;       // 41943042
// workspace byte offsets
constexpr size_t WS_IDX = 0;            // int[32768]
constexpr size_t WS_CNT = 131072;       // uint[1024]
constexpr size_t WS_LP  = 135168;       // float[1024]
constexpr size_t WS_E2  = 139264;       // float[1024]

constexpr float MARGIN = 7e-4f;         // >= 2*(fp16 dot err) + d-quantization slack

typedef _Float16 f16x8 __attribute__((ext_vector_type(8)));
typedef float    f32x4 __attribute__((ext_vector_type(4)));

__device__ inline unsigned fkey(float f) {
  unsigned u = __float_as_uint(f);
  return (u & 0x80000000u) ? ~u : (u | 0x80000000u);
}
__device__ inline float unfkey(unsigned k) {
  unsigned u = (k & 0x80000000u) ? (k ^ 0x80000000u) : ~k;
  return __uint_as_float(u);
}

// ---- e2[j] = sum_k emb[j][k]^2, fp64 accumulate -> fp32 (bit-matches R1-R5) ----
__global__ __launch_bounds__(64) void k_e2(const float* __restrict__ emb,
                                           float* __restrict__ e2) {
  const int j = blockIdx.x;
  const int t = threadIdx.x;
  const float* row = emb + (size_t)j * C_;
  double s = 0.0;
#pragma unroll
  for (int q = 0; q < 4; ++q) {
    float v = row[t + 64 * q];
    s += (double)v * (double)v;
  }
#pragma unroll
  for (int off = 32; off > 0; off >>= 1) s += __shfl_down(s, off);
  if (t == 0) e2[j] = (float)s;
}

// ---- codebook fp32 -> fp16 (RN), row-major [code][k] ----
__global__ __launch_bounds__(256) void k_ehl(const float* __restrict__ emb,
                                             _Float16* __restrict__ ehl) {
  const int i = blockIdx.x * 256 + threadIdx.x;   // 65536 float4 groups
  float4 v = reinterpret_cast<const float4*>(emb)[i];
  _Float16 h0 = (_Float16)v.x, h1 = (_Float16)v.y;
  _Float16 h2 = (_Float16)v.z, h3 = (_Float16)v.w;
  unsigned u0 = (unsigned)__builtin_bit_cast(unsigned short, h0) |
                ((unsigned)__builtin_bit_cast(unsigned short, h1) << 16);
  unsigned u1 = (unsigned)__builtin_bit_cast(unsigned short, h2) |
                ((unsigned)__builtin_bit_cast(unsigned short, h3) << 16);
  reinterpret_cast<uint2*>(ehl)[i] = make_uint2(u0, u1);
}

// ---- MFMA fp16 screen (lite): B fragments direct from global (L2), A in LDS.
// Same MFMA operand values/lanes as the R4/R5-verified version (swizzles cancel),
// so candidate sets are identical. LDS 137->73 KB (2 blocks/CU), barriers 16->6.
__global__ __launch_bounds__(512, 2) void k_screen(const float* __restrict__ z,
                                                   const _Float16* __restrict__ ehl,
                                                   const float* __restrict__ e2g,
                                                   unsigned short* __restrict__ cand_codes,
                                                   unsigned* __restrict__ cand_cnt) {
  __shared__ _Float16 Az[128 * 256];          // 64 KB
  __shared__ unsigned minkey[128];
  __shared__ unsigned ccnt[128];
  __shared__ unsigned short cand[128 * 32];   // 8 KB

  const int tid  = threadIdx.x;
  const int lane = tid & 63;
  const int wid  = tid >> 6;
  const int wr   = wid >> 2;          // 0..1 point half
  const int wc   = wid & 3;           // 0..3 code quarter (of chunk)
  const int l15  = lane & 15;
  const int lhi  = lane >> 4;         // 0..3
  const int n0   = blockIdx.x * 128;
  const int b    = blockIdx.x >> 3;
  const int l0   = (blockIdx.x & 7) << 7;

  const uint4* ehl4 = reinterpret_cast<const uint4*>(ehl);

  // A transpose+convert: z[b][k][l0+l'] fp32 -> Az[p][k] f16, XOR slot swizzle
  {
    const float4* z4 = reinterpret_cast<const float4*>(z + (size_t)b * (C_ * L_) + l0);
    const int l4 = tid & 31;
    const int kp = tid >> 5;
#pragma unroll
    for (int rr = 0; rr < 8; ++rr) {
      const int k0 = rr * 32 + kp * 2;
      float4 a0 = z4[(size_t)k0 * (L_ / 4) + l4];
      float4 a1 = z4[(size_t)(k0 + 1) * (L_ / 4) + l4];
      const float av0[4] = {a0.x, a0.y, a0.z, a0.w};
      const float av1[4] = {a1.x, a1.y, a1.z, a1.w};
#pragma unroll
      for (int j = 0; j < 4; ++j) {
        _Float16 h0 = (_Float16)av0[j];
        _Float16 h1 = (_Float16)av1[j];
        unsigned pk = (unsigned)__builtin_bit_cast(unsigned short, h0) |
                      ((unsigned)__builtin_bit_cast(unsigned short, h1) << 16);
        const int p = l4 * 4 + j;
        const int slot = k0 >> 3;
        const int addr = p * 256 + ((slot ^ (p & 31)) << 3) + (k0 & 7);
        *reinterpret_cast<unsigned*>(&Az[addr]) = pk;
      }
    }
  }
  if (tid < 128) { minkey[tid] = 0xFFFFFFFFu; ccnt[tid] = 0u; }
  __syncthreads();

  f32x4 acc[4][4];
#pragma unroll
  for (int i = 0; i < 4; ++i)
#pragma unroll
    for (int j = 0; j < 4; ++j) acc[i][j] = (f32x4){0.f, 0.f, 0.f, 0.f};

  for (int ph = 0; ph < 8; ++ph) {
    const int cc = ph >> 1;
    const int kh = ph & 1;
#pragma unroll
    for (int s = 0; s < 4; ++s) {
      const int slotA = kh * 16 + s * 4 + lhi;
      // B direct from global: lane needs ehl[code][k0 + 8*lhi .. +7] = one uint4
      f16x8 bfr[4];
#pragma unroll
      for (int tj = 0; tj < 4; ++tj)
        bfr[tj] = __builtin_bit_cast(f16x8,
            ehl4[(size_t)(cc * 256 + wc * 64 + tj * 16 + l15) * 32 +
                 kh * 16 + s * 4 + lhi]);
      f16x8 afr[4];
#pragma unroll
      for (int ti = 0; ti < 4; ++ti) {
        const int pA = wr * 64 + ti * 16 + l15;
        const int swzA = slotA ^ (((ti & 1) << 4) ^ l15);
        afr[ti] = *reinterpret_cast<const f16x8*>(&Az[pA * 256 + swzA * 8]);
      }
#pragma unroll
      for (int ti = 0; ti < 4; ++ti)
#pragma unroll
        for (int tj = 0; tj < 4; ++tj)
          acc[ti][tj] = __builtin_amdgcn_mfma_f32_16x16x32_f16(
              afr[ti], bfr[tj], acc[ti][tj], 0, 0, 0);
    }
    if (kh == 1) {
      float e2r[4];
#pragma unroll
      for (int tj = 0; tj < 4; ++tj)
        e2r[tj] = e2g[cc * 256 + wc * 64 + tj * 16 + l15];
#pragma unroll
      for (int ti = 0; ti < 4; ++ti) {
#pragma unroll
        for (int r = 0; r < 4; ++r) {
          float m = e2r[0] - 2.0f * acc[ti][0][r];
#pragma unroll
          for (int tj = 1; tj < 4; ++tj) {
            float v = e2r[tj] - 2.0f * acc[ti][tj][r];
            m = fminf(m, v);
          }
          m = fminf(m, __shfl_xor(m, 1));
          m = fminf(m, __shfl_xor(m, 2));
          m = fminf(m, __shfl_xor(m, 4));
          m = fminf(m, __shfl_xor(m, 8));
          if (l15 == 0) {
            const int p = wr * 64 + ti * 16 + lhi * 4 + r;
            atomicMin(&minkey[p], fkey(m));
          }
        }
      }
      __syncthreads();   // all waves' chunk-cc mins visible before extraction
      // threshold may only shrink from racing later chunks -> still a superset
      // that provably contains the exact argmin (thr >= global_min + MARGIN).
#pragma unroll
      for (int ti = 0; ti < 4; ++ti) {
#pragma unroll
        for (int r = 0; r < 4; ++r) {
          const int p = wr * 64 + ti * 16 + lhi * 4 + r;
          const float thr = unfkey(minkey[p]) + MARGIN;
#pragma unroll
          for (int tj = 0; tj < 4; ++tj) {
            float s = e2r[tj] - 2.0f * acc[ti][tj][r];
            if (s <= thr) {
              unsigned pos = atomicAdd(&ccnt[p], 1u);
              if (pos < 32u)
                cand[p * 32 + pos] = (unsigned short)(cc * 256 + wc * 64 + tj * 16 + l15);
            }
          }
        }
      }
#pragma unroll
      for (int i = 0; i < 4; ++i)
#pragma unroll
        for (int j = 0; j < 4; ++j) acc[i][j] = (f32x4){0.f, 0.f, 0.f, 0.f};
    }
  }
  __syncthreads();

  if (tid < 128) {
    const int n = n0 + tid;
    cand_cnt[n] = ccnt[tid];
    const unsigned* src = reinterpret_cast<const unsigned*>(&cand[tid * 32]);
    unsigned* dst = reinterpret_cast<unsigned*>(cand_codes) + (size_t)n * 16;
#pragma unroll
    for (int q = 0; q < 16; ++q) dst[q] = src[q];
  }
}

// ---- fused post: exact re-rank + z_q straight-through + masked loss ----
// 32 points/block, z staged once; winner via packed (fkey(d)|code) LDS atomicMin
// (order-independent, tie -> lower code); dot chain bit-identical to R1-R5.
__global__ __launch_bounds__(256, 2) void k_post(const float* __restrict__ z,
                                                 const float* __restrict__ emb,
                                                 const float* __restrict__ mask,
                                                 const float* __restrict__ e2g,
                                                 const unsigned short* __restrict__ cand_codes,
                                                 const unsigned* __restrict__ cand_cnt,
                                                 int* __restrict__ idxw,
                                                 unsigned* __restrict__ counts,
                                                 float* __restrict__ idx_out,
                                                 float* __restrict__ zq_out,
                                                 float* __restrict__ lp) {
  __shared__ float zs[256][34];          // 34.8 KB  [k][p]
  __shared__ float eq[256][34];          // 34.8 KB  [c][p] winner rows
  __shared__ unsigned long long bestkey[32];
  __shared__ float z2s[32];
  __shared__ int ids[32];
  __shared__ unsigned char dcnt[32];
  __shared__ int bad[32];
  __shared__ int nbad;
  __shared__ float red[256];
  __shared__ int rdi[256];

  const int tid = threadIdx.x, bid = blockIdx.x;
  const int b = bid >> 5, l0 = (bid & 31) << 5, n0 = bid << 5;

  // stage zs[k][p] = z[b][k][l0+p]  (float4 coalesced along l)
  {
    const float4* z4 = reinterpret_cast<const float4*>(z + (size_t)b * C_ * L_ + l0);
    const int l4 = tid & 7, kk = tid >> 3;
#pragma unroll
    for (int rep = 0; rep < 8; ++rep) {
      int k = rep * 32 + kk;
      float4 v = z4[(size_t)k * (L_ / 4) + l4];
      *reinterpret_cast<float4*>(&zs[k][l4 * 4]) = v;
    }
  }
  if (tid == 0) nbad = 0;
  __syncthreads();

  // classify + z2 (fp64 chain, bit-matches R1-R5)
  if (tid < 32) {
    const int n = n0 + tid;
    const unsigned cnt = cand_cnt[n];
    bestkey[tid] = ~0ULL;
    double s = 0.0;
#pragma unroll 8
    for (int k = 0; k < 256; ++k) {
      float v = zs[k][tid];
      s += (double)v * (double)v;
    }
    z2s[tid] = (float)s;
    if (cnt == 1u) {
      dcnt[tid] = 0;
      ids[tid] = cand_codes[(size_t)n * 32];
    } else if (cnt >= 2u && cnt <= 32u) {
      dcnt[tid] = (unsigned char)cnt;
    } else {                       // cnt==0 impossible; cnt>32 = overflow
      dcnt[tid] = 0;
      bad[atomicAdd(&nbad, 1)] = tid;
    }
  }
  __syncthreads();

  // exact dots: 8 threads per point, candidates q = j, j+8, ... (unordered ok)
  {
    const int p = tid >> 3, j = tid & 7;
    const int cnt = dcnt[p];
    const int n = n0 + p;
    for (int q = j; q < cnt; q += 8) {
      const int c = cand_codes[(size_t)n * 32 + q];
      const float4* er = reinterpret_cast<const float4*>(emb + (size_t)c * C_);
      float acc = 0.f;
#pragma unroll 4
      for (int k4 = 0; k4 < 64; ++k4) {
        float4 e = er[k4];
        acc = fmaf(zs[k4 * 4 + 0][p], e.x, acc);
        acc = fmaf(zs[k4 * 4 + 1][p], e.y, acc);
        acc = fmaf(zs[k4 * 4 + 2][p], e.z, acc);
        acc = fmaf(zs[k4 * 4 + 3][p], e.w, acc);
      }
      const float d = (z2s[p] + e2g[c]) - 2.0f * acc;   // numpy op order
      const unsigned long long key = ((unsigned long long)fkey(d) << 32) | (unsigned)c;
      atomicMin(&bestkey[p], key);
    }
  }
  __syncthreads();
  if (tid < 32 && dcnt[tid]) ids[tid] = (int)(unsigned)(bestkey[tid] & 0xFFFFFFFFu);

  // rare fallback: block-wide exact full scan for overflowed points
  if (nbad > 0) {
    __syncthreads();
    for (int ib = 0; ib < nbad; ++ib) {
      const int p = bad[ib];
      float bd = 3.4e38f;
      int bi = 0x7fffffff;
      for (int c = tid * 4; c < tid * 4 + 4; ++c) {
        const float* er = emb + (size_t)c * C_;
        float acc = 0.f;
        for (int k = 0; k < 256; ++k) acc = fmaf(zs[k][p], er[k], acc);
        const float d = (z2s[p] + e2g[c]) - 2.0f * acc;
        if (d < bd || (d == bd && c < bi)) { bd = d; bi = c; }
      }
      red[tid] = bd; rdi[tid] = bi;
      __syncthreads();
      for (int off = 128; off > 0; off >>= 1) {
        if (tid < off) {
          if (red[tid + off] < red[tid] ||
              (red[tid + off] == red[tid] && rdi[tid + off] < rdi[tid])) {
            red[tid] = red[tid + off]; rdi[tid] = rdi[tid + off];
          }
        }
        __syncthreads();
      }
      if (tid == 0) ids[p] = rdi[0];
      __syncthreads();
    }
  }
  __syncthreads();

  // finalize winners
  if (tid < 32) {
    const int n = n0 + tid;
    const int id = ids[tid];
    idxw[n] = id;
    idx_out[n] = (float)id;
    atomicAdd(&counts[id], 1u);
  }
  __syncthreads();

  // stage winner emb rows: eq[c][p] (coalesced 128 B per 8-lane group)
  {
    const int r = tid >> 3, kq = tid & 7;
    const float4* e4 = reinterpret_cast<const float4*>(emb + (size_t)ids[r] * C_);
#pragma unroll
    for (int rep = 0; rep < 8; ++rep) {
      int c4 = rep * 8 + kq;
      float4 v = e4[c4];
      eq[c4 * 4 + 0][r] = v.x;
      eq[c4 * 4 + 1][r] = v.y;
      eq[c4 * 4 + 2][r] = v.z;
      eq[c4 * 4 + 3][r] = v.w;
    }
  }
  __syncthreads();

  // z_q straight-through + masked loss partials (reads only LDS + mask)
  {
    const int lq = tid & 31, cg = tid >> 5;
    const float m = mask[b * L_ + l0 + lq];
    const size_t zbase = (size_t)b * C_ * L_ + l0 + lq;
    float s = 0.f;
#pragma unroll 4
    for (int ci = 0; ci < 32; ++ci) {
      int c = cg * 32 + ci;
      float zv = zs[c][lq];
      float q  = eq[c][lq];
      float diff = q - zv;                          // fl(z_q - zp)
      zq_out[zbase + (size_t)c * L_] = zv + diff;   // straight-through
      float t = diff * m;
      s = fmaf(t, t, s);
    }
    red[tid] = s;
  }
  __syncthreads();
  for (int off = 128; off > 0; off >>= 1) {
    if (tid < off) red[tid] += red[tid + off];
    __syncthreads();
  }
  if (tid == 0) lp[bid] = red[0];
}

// ---- one_hot: single pass, values on the fly (base only 8B-aligned) ----
__global__ __launch_bounds__(256) void k_onehot(const int* __restrict__ idxw,
                                                float* __restrict__ oh) {
  const int tid = threadIdx.x, bid = blockIdx.x;
#pragma unroll
  for (int r = 0; r < 16; ++r) {
    const int n = bid * 16 + r;
    const int id = idxw[n];
    float* row = oh + (size_t)n * NE;
    const int c = tid * 4;
    float2 v0, v1;
    v0.x = (c + 0 == id) ? 1.f : 0.f;
    v0.y = (c + 1 == id) ? 1.f : 0.f;
    v1.x = (c + 2 == id) ? 1.f : 0.f;
    v1.y = (c + 3 == id) ? 1.f : 0.f;
    *reinterpret_cast<float2*>(row + c)     = v0;
    *reinterpret_cast<float2*>(row + c + 2) = v1;
  }
}

// ---- deterministic loss total + perplexity (lp now 1024 entries) ----
__global__ __launch_bounds__(256) void k_final(const float* __restrict__ lp,
                                               const unsigned int* __restrict__ counts,
                                               float* __restrict__ out) {
  __shared__ float red[256];
  const int t = threadIdx.x;
  red[t] = lp[t] + lp[t + 256] + lp[t + 512] + lp[t + 768];
  __syncthreads();
  for (int off = 128; off > 0; off >>= 1) {
    if (t < off) red[t] += red[t + off];
    __syncthreads();
  }
  if (t == 0) {
    float m = red[0] / 8388608.0f;
    out[LOSS_OFF] = m + 0.25f * m;
  }
  __syncthreads();
  float h = 0.f;
#pragma unroll
  for (int q = 0; q < 4; ++q) {
    int jj = t * 4 + q;
    float em = (float)counts[jj] * (1.0f / 32768.0f);
    h += em * logf(em + 1e-10f);
  }
  red[t] = h;
  __syncthreads();
  for (int off = 128; off > 0; off >>= 1) {
    if (t < off) red[t] += red[t + off];
    __syncthreads();
  }
  if (t == 0) out[PERP_OFF] = expf(-red[0]);
}

extern "C" void kernel_launch(void* const* d_in, const int* in_sizes, int n_in,
                              void* d_out, int out_size, void* d_ws, size_t ws_size,
                              hipStream_t stream) {
  const float* z    = (const float*)d_in[0];
  const float* mask = (const float*)d_in[1];
  const float* emb  = (const float*)d_in[2];
  float* out = (float*)d_out;
  char* ws = (char*)d_ws;
  int* idxw            = (int*)(ws + WS_IDX);
  unsigned int* counts = (unsigned int*)(ws + WS_CNT);
  float* lp            = (float*)(ws + WS_LP);
  float* e2            = (float*)(ws + WS_E2);

  // big scratch inside the one_hot output region; k_onehot (which overwrites
  // it) runs strictly after all readers on the same stream.
  uintptr_t sp = (uintptr_t)(out + OH_OFF);
  sp = (sp + 15) & ~(uintptr_t)15;
  _Float16* ehl              = (_Float16*)sp;                              // 512 KB
  unsigned short* cand_codes = (unsigned short*)(sp + 524288);             // 2 MB
  unsigned* cand_cnt         = (unsigned*)(sp + 524288 + 2097152);         // 128 KB

  hipMemsetAsync(counts, 0, NE * sizeof(unsigned int), stream);
  hipLaunchKernelGGL(k_e2, dim3(NE), dim3(64), 0, stream, emb, e2);
  hipLaunchKernelGGL(k_ehl, dim3(256), dim3(256), 0, stream, emb, ehl);
  hipLaunchKernelGGL(k_screen, dim3(256), dim3(512), 0, stream,
                     z, ehl, e2, cand_codes, cand_cnt);
  hipLaunchKernelGGL(k_post, dim3(1024), dim3(256), 0, stream,
                     z, emb, mask, e2, cand_codes, cand_cnt,
                     idxw, counts, out + IDX_OFF, out + ZQ_OFF, lp);
  hipLaunchKernelGGL(k_onehot, dim3(NPTS / 16), dim3(256), 0, stream,
                     idxw, out + OH_OFF);
  hipLaunchKernelGGL(k_final, dim3(1), dim3(256), 0, stream, lp, counts, out);
}